// Round 1
// baseline (3933.296 us; speedup 1.0000x reference)
//
#include <hip/hip_runtime.h>
#include <cstdint>
#include <cstddef>

typedef __attribute__((ext_vector_type(4))) float f32x4;
typedef __attribute__((ext_vector_type(8))) short short8;
typedef unsigned short u16;

#define DEVINL static __device__ __forceinline__

constexpr int NBATCH = 4;
constexpr int NSEQ   = 1024;
constexpr int NDIM   = 512;
constexpr int NHEAD  = 8;
constexpr int NDH    = 64;
constexpr int NMLP   = 2048;
constexpr int NROWS  = NBATCH * NSEQ;   // 4096
constexpr int NBLKC  = 32;              // compressed blocks
constexpr int NBH    = NBATCH * NHEAD;  // 32

DEVINL float b2f(u16 u) { union { unsigned u; float f; } x; x.u = ((unsigned)u) << 16; return x.f; }
DEVINL u16 f2b(float v) {
    union { float f; unsigned u; } x; x.f = v;
    unsigned r = x.u + 0x7fff + ((x.u >> 16) & 1);
    return (u16)(r >> 16);
}

// ---------------- LayerNorm -> bf16 ----------------
__global__ void __launch_bounds__(256) ln_kernel(const float* __restrict__ x,
    const float* __restrict__ gg, const float* __restrict__ bb, u16* __restrict__ out)
{
    int row = blockIdx.x * 4 + (threadIdx.x >> 6);
    int lane = threadIdx.x & 63;
    const float* xr = x + (size_t)row * NDIM + lane * 8;
    f32x4 a = *(const f32x4*)xr;
    f32x4 c = *(const f32x4*)(xr + 4);
    float xv[8] = { a[0], a[1], a[2], a[3], c[0], c[1], c[2], c[3] };
    float s = 0.f, s2 = 0.f;
    #pragma unroll
    for (int i = 0; i < 8; ++i) { s += xv[i]; s2 += xv[i] * xv[i]; }
    #pragma unroll
    for (int d = 1; d < 64; d <<= 1) { s += __shfl_xor(s, d); s2 += __shfl_xor(s2, d); }
    float mean = s * (1.f / NDIM);
    float var = s2 * (1.f / NDIM) - mean * mean;
    float rstd = rsqrtf(var + 1e-5f);
    const float* gp = gg + lane * 8;
    const float* bp = bb + lane * 8;
    short8 o;
    #pragma unroll
    for (int i = 0; i < 8; ++i)
        o[i] = (short)f2b((xv[i] - mean) * rstd * gp[i] + bp[i]);
    *(short8*)(out + (size_t)row * NDIM + lane * 8) = o;
}

// ---------------- weight transpose fp32[K][Nc] -> bf16[Nc][K] ----------------
__global__ void __launch_bounds__(256) transpose_w(const float* __restrict__ W,
    u16* __restrict__ WT, int K, int Nc)
{
    __shared__ float tile[32][33];
    int tx = threadIdx.x & 31;
    int ty = threadIdx.x >> 5;     // 0..7
    int n0 = blockIdx.x * 32, k0 = blockIdx.y * 32;
    #pragma unroll
    for (int r = 0; r < 4; ++r) {
        int kr = ty * 4 + r;
        tile[kr][tx] = W[(size_t)(k0 + kr) * Nc + n0 + tx];
    }
    __syncthreads();
    #pragma unroll
    for (int r = 0; r < 4; ++r) {
        int nr = ty * 4 + r;
        WT[(size_t)(n0 + nr) * K + k0 + tx] = f2b(tile[tx][nr]);
    }
}

// ---------------- gates = sigmoid(h @ Wg + bg) ----------------
__global__ void __launch_bounds__(256) gates_kernel(const u16* __restrict__ h,
    const float* __restrict__ Wg, const float* __restrict__ bg, float* __restrict__ gates)
{
    int idx = blockIdx.x * 256 + threadIdx.x;
    if (idx >= NROWS * NHEAD * 3) return;
    int row = idx / 24, c = idx - row * 24;
    const u16* hr = h + (size_t)row * NDIM;
    float s = bg[c];
    for (int kk = 0; kk < NDIM; ++kk)
        s += b2f(hr[kk]) * Wg[(size_t)kk * 24 + c];
    gates[idx] = 1.f / (1.f + expf(-s));
}

// ---------------- block mean-pool of K/V ----------------
__global__ void __launch_bounds__(256) pool_kernel(const float* __restrict__ k,
    const float* __restrict__ v, float* __restrict__ kc, float* __restrict__ vc)
{
    int idx = blockIdx.x * 256 + threadIdx.x; // 32*32*64 = 65536
    int d = idx & 63, m = (idx >> 6) & 31, bh = idx >> 11;
    const float* kb = k + ((size_t)bh * NSEQ + m * 32) * NDH + d;
    const float* vb = v + ((size_t)bh * NSEQ + m * 32) * NDH + d;
    float sk = 0.f, sv = 0.f;
    #pragma unroll 8
    for (int j = 0; j < 32; ++j) { sk += kb[j * NDH]; sv += vb[j * NDH]; }
    kc[(size_t)bh * (NBLKC * NDH) + m * NDH + d] = sk * (1.f / 32.f);
    vc[(size_t)bh * (NBLKC * NDH) + m * NDH + d] = sv * (1.f / 32.f);
}

// ---------------- bf16 MFMA GEMM: C = A[M,K] @ (BT[Nc,K])^T ----------------
enum { EP_QKV = 0, EP_GELU = 1, EP_RES = 2 };

template<int BM, int BN, int EPIL>
__global__ void __launch_bounds__(256) gemm_k(
    const u16* __restrict__ A, const u16* __restrict__ BT,
    int M, int Nc, int K,
    const float* __restrict__ bias,
    float* __restrict__ resout,        // EP_RES: fp32 in/out (residual +=)
    u16* __restrict__ outb,            // EP_GELU: bf16 out [M][Nc]
    float* __restrict__ oq, float* __restrict__ ok2, float* __restrict__ ov)
{
    constexpr int BK = 32;
    constexpr int WM = BM / 2, WN = BN / 2;
    constexpr int MI = WM / 16, NI = WN / 16;
    __shared__ u16 As[BM][BK + 8];
    __shared__ u16 Bs[BN][BK + 8];
    const int tid = threadIdx.x;
    const int lane = tid & 63;
    const int wid = tid >> 6;
    const int wm = wid >> 1, wn = wid & 1;
    const int rowBase = blockIdx.y * BM;
    const int colBase = blockIdx.x * BN;
    const int fr = lane & 15;
    const int kg = lane >> 4;
    const int sr = tid >> 2;
    const int sk = (tid & 3) * 8;
    f32x4 acc[MI][NI] = {};

    for (int k0 = 0; k0 < K; k0 += BK) {
        __syncthreads();
        #pragma unroll
        for (int c = 0; c < BM / 64; ++c) {
            int r = c * 64 + sr;
            *(f32x4*)(&As[r][sk]) = *(const f32x4*)(&A[(size_t)(rowBase + r) * K + k0 + sk]);
        }
        #pragma unroll
        for (int c = 0; c < BN / 64; ++c) {
            int r = c * 64 + sr;
            *(f32x4*)(&Bs[r][sk]) = *(const f32x4*)(&BT[(size_t)(colBase + r) * K + k0 + sk]);
        }
        __syncthreads();
        short8 af[MI], bfr[NI];
        #pragma unroll
        for (int i = 0; i < MI; ++i)
            af[i] = *(const short8*)(&As[wm * WM + i * 16 + fr][kg * 8]);
        #pragma unroll
        for (int j = 0; j < NI; ++j)
            bfr[j] = *(const short8*)(&Bs[wn * WN + j * 16 + fr][kg * 8]);
        #pragma unroll
        for (int i = 0; i < MI; ++i)
            #pragma unroll
            for (int j = 0; j < NI; ++j)
                acc[i][j] = __builtin_amdgcn_mfma_f32_16x16x32_bf16(af[i], bfr[j], acc[i][j], 0, 0, 0);
    }

    #pragma unroll
    for (int i = 0; i < MI; ++i) {
        #pragma unroll
        for (int j = 0; j < NI; ++j) {
            int col = colBase + wn * WN + j * 16 + fr;
            #pragma unroll
            for (int rr = 0; rr < 4; ++rr) {
                int row = rowBase + wm * WM + i * 16 + kg * 4 + rr;
                float val = acc[i][j][rr];
                if constexpr (EPIL == EP_QKV) {
                    int which = col >> 9, c = col & 511;
                    int hh = c >> 6, dh = c & 63;
                    int b = row >> 10, n = row & 1023;
                    size_t o = ((size_t)(b * NHEAD + hh) * NSEQ + n) * NDH + dh;
                    if (which == 0)      oq[o]  = val * 0.125f;   // q * DH^-0.5
                    else if (which == 1) ok2[o] = val;
                    else                 ov[o]  = val;
                } else if constexpr (EPIL == EP_GELU) {
                    float t = val + bias[col];
                    float g = 0.5f * t * (1.f + tanhf(0.7978845608f * (t + 0.044715f * t * t * t)));
                    outb[(size_t)row * Nc + col] = f2b(g);
                } else {
                    resout[(size_t)row * Nc + col] += val + bias[col];
                }
            }
        }
    }
}

// ---------------- sparse attention: one wave per query ----------------
DEVINL float dot64(const float* qp, const float* kp)
{
    float s = 0.f;
    #pragma unroll
    for (int i = 0; i < 16; ++i) {
        f32x4 kv = *(const f32x4*)(kp + i * 4);
        f32x4 qv = *(const f32x4*)(qp + i * 4);
        s += qv[0] * kv[0] + qv[1] * kv[1] + qv[2] * kv[2] + qv[3] * kv[3];
    }
    return s;
}

__global__ void __launch_bounds__(256) attn_kernel(
    const float* __restrict__ q, const float* __restrict__ k, const float* __restrict__ v,
    const float* __restrict__ kc, const float* __restrict__ vc,
    const float* __restrict__ gates, u16* __restrict__ att)
{
    __shared__ float qs[4][64];
    const int wid = threadIdx.x >> 6;
    const int lane = threadIdx.x & 63;
    // XCD-aware swizzle: each XCD (blockIdx&7) owns 4 consecutive bh -> KV fits its L2
    int B0 = blockIdx.x;                 // 0..8191
    int xcd = B0 & 7, i = B0 >> 3;       // i: 0..1023
    int bh = xcd * 4 + (i >> 8);
    int blkin = i & 255;
    int qi = bh * NSEQ + blkin * 4 + wid;
    int n = qi & (NSEQ - 1);
    int b = bh >> 3, hh = bh & 7;

    qs[wid][lane] = q[(size_t)qi * NDH + lane];
    __syncthreads();
    const float* qsw = qs[wid];
    const float* ks = k + (size_t)bh * NSEQ * NDH;
    const float* vs = v + (size_t)bh * NSEQ * NDH;
    const float* kcs = kc + (size_t)bh * NBLKC * NDH;
    const float* vcs = vc + (size_t)bh * NBLKC * NDH;

    // ---- compressed branch: scores over 32 block-means
    const int m = lane & 31, half = lane >> 5;
    float part = 0.f;
    {
        const float* kr = kcs + m * NDH + half * 32;
        const float* qh = qsw + half * 32;
        #pragma unroll
        for (int i2 = 0; i2 < 8; ++i2) {
            f32x4 kv = *(const f32x4*)(kr + i2 * 4);
            f32x4 qv = *(const f32x4*)(qh + i2 * 4);
            part += qv[0] * kv[0] + qv[1] * kv[1] + qv[2] * kv[2] + qv[3] * kv[3];
        }
    }
    float sc = part + __shfl_xor(part, 32);     // lanes duplicated across halves
    float mxc = sc;
    #pragma unroll
    for (int d = 1; d < 32; d <<= 1) mxc = fmaxf(mxc, __shfl_xor(mxc, d));
    float pc = expf(sc - mxc);
    float denc = pc;
    #pragma unroll
    for (int d = 1; d < 32; d <<= 1) denc += __shfl_xor(denc, d);
    float oc = 0.f;
    #pragma unroll 4
    for (int mm = 0; mm < 32; ++mm) {
        float p = __shfl(pc, mm);
        oc += p * vcs[mm * NDH + lane];
    }
    oc /= denc;

    // ---- top-8 blocks (set semantics; min-index tie-break)
    int sel[8];
    float cur = sc;
    #pragma unroll
    for (int t = 0; t < 8; ++t) {
        float val = cur; int idx = m;
        #pragma unroll
        for (int d = 1; d < 32; d <<= 1) {
            float ovv = __shfl_xor(val, d);
            int oi = __shfl_xor(idx, d);
            if (ovv > val || (ovv == val && oi < idx)) { val = ovv; idx = oi; }
        }
        sel[t] = idx;
        if (m == idx) cur = -3.4e38f;
    }

    // ---- selection branch: 8 blocks * 32 keys = 256 keys
    float ps4[4];
    const int t32 = lane & 31;
    #pragma unroll
    for (int c = 0; c < 4; ++c) {
        int bsel = (lane < 32) ? sel[2 * c] : sel[2 * c + 1];
        int tok = bsel * 32 + t32;
        ps4[c] = dot64(qsw, ks + (size_t)tok * NDH);
    }
    float mxs = fmaxf(fmaxf(ps4[0], ps4[1]), fmaxf(ps4[2], ps4[3]));
    #pragma unroll
    for (int d = 1; d < 64; d <<= 1) mxs = fmaxf(mxs, __shfl_xor(mxs, d));
    float dens = 0.f;
    #pragma unroll
    for (int c = 0; c < 4; ++c) { ps4[c] = expf(ps4[c] - mxs); dens += ps4[c]; }
    #pragma unroll
    for (int d = 1; d < 64; d <<= 1) dens += __shfl_xor(dens, d);
    float os = 0.f;
    #pragma unroll
    for (int blk = 0; blk < 8; ++blk) {
        const float* vblk = vs + (size_t)sel[blk] * 32 * NDH;
        for (int jj = 0; jj < 32; ++jj) {
            float p = __shfl(ps4[blk >> 1], ((blk & 1) << 5) | jj);
            os += p * vblk[jj * NDH + lane];
        }
    }
    os /= dens;

    // ---- sliding window branch: |i-j| <= 32
    int wstart = n - 32; if (wstart < 0) wstart = 0;
    int wend = n + 32; if (wend > NSEQ - 1) wend = NSEQ - 1;
    float pw[2];
    #pragma unroll
    for (int c = 0; c < 2; ++c) {
        int tok = wstart + c * 64 + lane;
        pw[c] = (tok <= wend) ? dot64(qsw, ks + (size_t)tok * NDH) : -3.4e38f;
    }
    float mxw = fmaxf(pw[0], pw[1]);
    #pragma unroll
    for (int d = 1; d < 64; d <<= 1) mxw = fmaxf(mxw, __shfl_xor(mxw, d));
    float denw = 0.f;
    #pragma unroll
    for (int c = 0; c < 2; ++c) { pw[c] = expf(pw[c] - mxw); denw += pw[c]; }
    #pragma unroll
    for (int d = 1; d < 64; d <<= 1) denw += __shfl_xor(denw, d);
    float ow = 0.f;
    #pragma unroll
    for (int c = 0; c < 2; ++c) {
        for (int jj = 0; jj < 64; ++jj) {
            int tok = wstart + c * 64 + jj;
            if (tok > wend) break;
            float p = __shfl(pw[c], jj);
            ow += p * vs[(size_t)tok * NDH + lane];
        }
    }
    ow /= denw;

    // ---- gate & combine
    const float* grow = gates + ((size_t)(b * NSEQ + n) * 24 + hh * 3);
    float o = grow[0] * oc + grow[1] * os + grow[2] * ow;
    att[(size_t)(b * NSEQ + n) * NDIM + hh * NDH + lane] = f2b(o);
}

// ---------------- host ----------------
extern "C" void kernel_launch(void* const* d_in, const int* in_sizes, int n_in,
                              void* d_out, int out_size, void* d_ws, size_t ws_size,
                              hipStream_t stream)
{
    const float* x0    = (const float*)d_in[0];
    const float* ln1_g = (const float*)d_in[1];
    const float* ln1_b = (const float*)d_in[2];
    const float* Wq    = (const float*)d_in[3];
    const float* Wk    = (const float*)d_in[4];
    const float* Wv    = (const float*)d_in[5];
    const float* Wg    = (const float*)d_in[6];
    const float* bg    = (const float*)d_in[7];
    const float* Wo    = (const float*)d_in[8];
    const float* bo    = (const float*)d_in[9];
    const float* ln2_g = (const float*)d_in[10];
    const float* ln2_b = (const float*)d_in[11];
    const float* W1    = (const float*)d_in[12];
    const float* b1    = (const float*)d_in[13];
    const float* W2    = (const float*)d_in[14];
    const float* b2    = (const float*)d_in[15];
    float* xo = (float*)d_out;

    char* w = (char*)d_ws;
    auto alloc = [&](size_t bytes) { char* p = w; w += (bytes + 255) & ~(size_t)255; return p; };
    u16*   hbf   = (u16*)  alloc((size_t)NROWS * NDIM * 2);
    float* qb    = (float*)alloc((size_t)NROWS * NDIM * 4);
    float* kb    = (float*)alloc((size_t)NROWS * NDIM * 4);
    float* vb    = (float*)alloc((size_t)NROWS * NDIM * 4);
    u16*   att   = (u16*)  alloc((size_t)NROWS * NDIM * 2);
    float* gates = (float*)alloc((size_t)NROWS * NHEAD * 3 * 4);
    float* kc    = (float*)alloc((size_t)NBH * NBLKC * NDH * 4);
    float* vc    = (float*)alloc((size_t)NBH * NBLKC * NDH * 4);
    u16*   wqkvT = (u16*)  alloc((size_t)2 * 1536 * 512 * 2);
    u16*   woT   = (u16*)  alloc((size_t)2 * 512 * 512 * 2);
    u16*   w1T   = (u16*)  alloc((size_t)2 * 2048 * 512 * 2);
    u16*   w2T   = (u16*)  alloc((size_t)2 * 512 * 2048 * 2);
    u16*   mid   = (u16*)qb;  // alias: q/k dead during MLP

    hipMemcpyAsync(xo, x0, (size_t)NROWS * NDIM * 4, hipMemcpyDeviceToDevice, stream);

    for (int l = 0; l < 2; ++l) {
        transpose_w<<<dim3(16, 16), 256, 0, stream>>>(Wq + (size_t)l * 512 * 512, wqkvT + (size_t)l * 1536 * 512,              512, 512);
        transpose_w<<<dim3(16, 16), 256, 0, stream>>>(Wk + (size_t)l * 512 * 512, wqkvT + (size_t)l * 1536 * 512 + 512 * 512,  512, 512);
        transpose_w<<<dim3(16, 16), 256, 0, stream>>>(Wv + (size_t)l * 512 * 512, wqkvT + (size_t)l * 1536 * 512 + 1024 * 512, 512, 512);
        transpose_w<<<dim3(16, 16), 256, 0, stream>>>(Wo + (size_t)l * 512 * 512, woT + (size_t)l * 512 * 512,                 512, 512);
        transpose_w<<<dim3(64, 16), 256, 0, stream>>>(W1 + (size_t)l * 512 * 2048, w1T + (size_t)l * 2048 * 512,               512, 2048);
        transpose_w<<<dim3(16, 64), 256, 0, stream>>>(W2 + (size_t)l * 2048 * 512, w2T + (size_t)l * 512 * 2048,               2048, 512);
    }

    for (int l = 0; l < 2; ++l) {
        ln_kernel<<<NROWS / 4, 256, 0, stream>>>(xo, ln1_g + l * NDIM, ln1_b + l * NDIM, hbf);
        gates_kernel<<<(NROWS * NHEAD * 3) / 256, 256, 0, stream>>>(hbf, Wg + (size_t)l * NDIM * 24, bg + l * 24, gates);
        gemm_k<128, 128, EP_QKV><<<dim3(1536 / 128, NROWS / 128), 256, 0, stream>>>(
            hbf, wqkvT + (size_t)l * 1536 * 512, NROWS, 1536, 512,
            nullptr, nullptr, nullptr, qb, kb, vb);
        pool_kernel<<<(NBH * NBLKC * NDH) / 256, 256, 0, stream>>>(kb, vb, kc, vc);
        attn_kernel<<<NROWS * NHEAD / 4, 256, 0, stream>>>(qb, kb, vb, kc, vc, gates, att);
        gemm_k<64, 64, EP_RES><<<dim3(512 / 64, NROWS / 64), 256, 0, stream>>>(
            att, woT + (size_t)l * 512 * 512, NROWS, 512, 512,
            bo + l * NDIM, xo, nullptr, nullptr, nullptr, nullptr);
        ln_kernel<<<NROWS / 4, 256, 0, stream>>>(xo, ln2_g + l * NDIM, ln2_b + l * NDIM, hbf);
        gemm_k<128, 128, EP_GELU><<<dim3(2048 / 128, NROWS / 128), 256, 0, stream>>>(
            hbf, w1T + (size_t)l * 2048 * 512, NROWS, 2048, 512,
            b1 + l * NMLP, nullptr, mid, nullptr, nullptr, nullptr);
        gemm_k<64, 64, EP_RES><<<dim3(512 / 64, NROWS / 64), 256, 0, stream>>>(
            mid, w2T + (size_t)l * 512 * 2048, NROWS, 512, 2048,
            b2 + l * NDIM, xo, nullptr, nullptr, nullptr, nullptr);
    }
}

// Round 3
// 526.610 us; speedup vs baseline: 7.4691x; 7.4691x over previous
//
#include <hip/hip_runtime.h>
#include <cstdint>
#include <cstddef>

typedef __attribute__((ext_vector_type(4))) float f32x4;
typedef __attribute__((ext_vector_type(16))) float f32x16;
typedef __attribute__((ext_vector_type(8))) short short8;
typedef __attribute__((ext_vector_type(4))) short s16x4;
typedef unsigned short u16;

#define DEVINL static __device__ __forceinline__
#define MFMA32(A,B,C) __builtin_amdgcn_mfma_f32_32x32x16_bf16(A,B,C,0,0,0)

constexpr int NBATCH = 4;
constexpr int NSEQ   = 1024;
constexpr int NDIM   = 512;
constexpr int NHEAD  = 8;
constexpr int NDH    = 64;
constexpr int NMLP   = 2048;
constexpr int NROWS  = NBATCH * NSEQ;   // 4096
constexpr int NBLKC  = 32;
constexpr int NBH    = NBATCH * NHEAD;  // 32

DEVINL float b2f(u16 u) { union { unsigned u; float f; } x; x.u = ((unsigned)u) << 16; return x.f; }
DEVINL u16 f2b(float v) {
    union { float f; unsigned u; } x; x.f = v;
    unsigned r = x.u + 0x7fff + ((x.u >> 16) & 1);
    return (u16)(r >> 16);
}

// ---------------- LayerNorm -> bf16 ----------------
__global__ void __launch_bounds__(256) ln_kernel(const float* __restrict__ x,
    const float* __restrict__ gg, const float* __restrict__ bb, u16* __restrict__ out)
{
    int row = blockIdx.x * 4 + (threadIdx.x >> 6);
    int lane = threadIdx.x & 63;
    const float* xr = x + (size_t)row * NDIM + lane * 8;
    f32x4 a = *(const f32x4*)xr;
    f32x4 c = *(const f32x4*)(xr + 4);
    float xv[8] = { a[0], a[1], a[2], a[3], c[0], c[1], c[2], c[3] };
    float s = 0.f, s2 = 0.f;
    #pragma unroll
    for (int i = 0; i < 8; ++i) { s += xv[i]; s2 += xv[i] * xv[i]; }
    #pragma unroll
    for (int d = 1; d < 64; d <<= 1) { s += __shfl_xor(s, d); s2 += __shfl_xor(s2, d); }
    float mean = s * (1.f / NDIM);
    float var = s2 * (1.f / NDIM) - mean * mean;
    float rstd = rsqrtf(var + 1e-5f);
    const float* gp = gg + lane * 8;
    const float* bp = bb + lane * 8;
    short8 o;
    #pragma unroll
    for (int i = 0; i < 8; ++i)
        o[i] = (short)f2b((xv[i] - mean) * rstd * gp[i] + bp[i]);
    *(short8*)(out + (size_t)row * NDIM + lane * 8) = o;
}

// ---------------- weight transpose fp32[K][Nc] -> bf16[Nc][K] ----------------
__global__ void __launch_bounds__(256) transpose_w(const float* __restrict__ W,
    u16* __restrict__ WT, int K, int Nc)
{
    __shared__ float tile[32][33];
    int tx = threadIdx.x & 31;
    int ty = threadIdx.x >> 5;
    int n0 = blockIdx.x * 32, k0 = blockIdx.y * 32;
    #pragma unroll
    for (int r = 0; r < 4; ++r) {
        int kr = ty * 4 + r;
        tile[kr][tx] = W[(size_t)(k0 + kr) * Nc + n0 + tx];
    }
    __syncthreads();
    #pragma unroll
    for (int r = 0; r < 4; ++r) {
        int nr = ty * 4 + r;
        WT[(size_t)(n0 + nr) * K + k0 + tx] = f2b(tile[tx][nr]);
    }
}

// ---------------- gates = sigmoid(h @ Wg + bg): one wave per row ----------------
__global__ void __launch_bounds__(256) gates_kernel(const u16* __restrict__ h,
    const float* __restrict__ Wg, const float* __restrict__ bg, float* __restrict__ gates)
{
    int wid = threadIdx.x >> 6, lane = threadIdx.x & 63;
    int row = blockIdx.x * 4 + wid;
    short8 hv = *(const short8*)(h + (size_t)row * NDIM + lane * 8);
    float acc[24];
    #pragma unroll
    for (int c = 0; c < 24; ++c) acc[c] = 0.f;
    const float* wg = Wg + (size_t)(lane * 8) * 24;
    #pragma unroll
    for (int j = 0; j < 8; ++j) {
        float hj = b2f((u16)hv[j]);
        const float* wr = wg + j * 24;
        #pragma unroll
        for (int c = 0; c < 24; ++c) acc[c] += hj * wr[c];
    }
    #pragma unroll
    for (int d = 1; d < 64; d <<= 1) {
        #pragma unroll
        for (int c = 0; c < 24; ++c) acc[c] += __shfl_xor(acc[c], d);
    }
    float v = 0.f;
    #pragma unroll
    for (int c = 0; c < 24; ++c) if (lane == c) v = acc[c];
    if (lane < 24)
        gates[(size_t)row * 24 + lane] = 1.f / (1.f + __expf(-(v + bg[lane])));
}

// ---------------- block mean-pool of K/V (bf16 inputs) ----------------
__global__ void __launch_bounds__(256) pool_kernel(const u16* __restrict__ kb,
    const u16* __restrict__ vt, float* __restrict__ kc, float* __restrict__ vc)
{
    int idx = blockIdx.x * 256 + threadIdx.x; // 65536
    int d = idx & 63, m = (idx >> 6) & 31, bh = idx >> 11;
    const u16* kp = kb + ((size_t)bh * NSEQ + m * 32) * NDH + d;
    float sk = 0.f;
    #pragma unroll 8
    for (int j = 0; j < 32; ++j) sk += b2f(kp[j * NDH]);
    const u16* vp = vt + (size_t)bh * 65536 + (size_t)d * NSEQ + m * 32;
    float sv = 0.f;
    #pragma unroll 8
    for (int j = 0; j < 32; ++j) sv += b2f(vp[j]);
    kc[(size_t)bh * 2048 + m * 64 + d] = sk * (1.f / 32.f);
    vc[(size_t)bh * 2048 + m * 64 + d] = sv * (1.f / 32.f);
}

// ---------------- bf16 MFMA GEMM: C = A[M,K] @ (BT[Nc,K])^T ----------------
enum { EP_QKV = 0, EP_GELU = 1, EP_RES = 2 };

template<int BM, int BN, int EPIL>
__global__ void __launch_bounds__(256) gemm_k(
    const u16* __restrict__ A, const u16* __restrict__ BT,
    int M, int Nc, int K,
    const float* __restrict__ bias,
    float* __restrict__ resout,
    u16* __restrict__ outb,
    u16* __restrict__ q16, u16* __restrict__ k16, u16* __restrict__ vt16)
{
    constexpr int BK = 32;
    constexpr int WM = BM / 2, WN = BN / 2;
    constexpr int MI = WM / 16, NI = WN / 16;
    __shared__ u16 As[BM][BK + 8];
    __shared__ u16 Bs[BN][BK + 8];
    const int tid = threadIdx.x;
    const int lane = tid & 63;
    const int wid = tid >> 6;
    const int wm = wid >> 1, wn = wid & 1;
    const int rowBase = blockIdx.y * BM;
    const int colBase = blockIdx.x * BN;
    const int fr = lane & 15;
    const int kg = lane >> 4;
    const int sr = tid >> 2;
    const int sk = (tid & 3) * 8;
    f32x4 acc[MI][NI] = {};

    for (int k0 = 0; k0 < K; k0 += BK) {
        __syncthreads();
        #pragma unroll
        for (int c = 0; c < BM / 64; ++c) {
            int r = c * 64 + sr;
            *(f32x4*)(&As[r][sk]) = *(const f32x4*)(&A[(size_t)(rowBase + r) * K + k0 + sk]);
        }
        #pragma unroll
        for (int c = 0; c < BN / 64; ++c) {
            int r = c * 64 + sr;
            *(f32x4*)(&Bs[r][sk]) = *(const f32x4*)(&BT[(size_t)(colBase + r) * K + k0 + sk]);
        }
        __syncthreads();
        short8 af[MI], bfr[NI];
        #pragma unroll
        for (int i = 0; i < MI; ++i)
            af[i] = *(const short8*)(&As[wm * WM + i * 16 + fr][kg * 8]);
        #pragma unroll
        for (int j = 0; j < NI; ++j)
            bfr[j] = *(const short8*)(&Bs[wn * WN + j * 16 + fr][kg * 8]);
        #pragma unroll
        for (int i = 0; i < MI; ++i)
            #pragma unroll
            for (int j = 0; j < NI; ++j)
                acc[i][j] = __builtin_amdgcn_mfma_f32_16x16x32_bf16(af[i], bfr[j], acc[i][j], 0, 0, 0);
    }

    #pragma unroll
    for (int i = 0; i < MI; ++i) {
        #pragma unroll
        for (int j = 0; j < NI; ++j) {
            int col = colBase + wn * WN + j * 16 + fr;
            if constexpr (EPIL == EP_QKV) {
                int which = col >> 9, c = col & 511;
                int hh = c >> 6, dh = c & 63;
                int row0 = rowBase + wm * WM + i * 16 + kg * 4;
                int bb2 = row0 >> 10, n0 = row0 & 1023;
                size_t bh2 = (size_t)(bb2 * NHEAD + hh) * 65536;
                if (which == 2) {
                    s16x4 pk;
                    #pragma unroll
                    for (int rr = 0; rr < 4; ++rr) pk[rr] = (short)f2b(acc[i][j][rr]);
                    *(s16x4*)&vt16[bh2 + (size_t)dh * NSEQ + n0] = pk;
                } else {
                    u16* dst = (which ? k16 : q16) + bh2 + (size_t)n0 * NDH + dh;
                    float scl = which ? 1.f : 0.125f;
                    #pragma unroll
                    for (int rr = 0; rr < 4; ++rr) dst[rr * NDH] = f2b(acc[i][j][rr] * scl);
                }
            } else {
                #pragma unroll
                for (int rr = 0; rr < 4; ++rr) {
                    int row = rowBase + wm * WM + i * 16 + kg * 4 + rr;
                    float val = acc[i][j][rr];
                    if constexpr (EPIL == EP_GELU) {
                        float t = val + bias[col];
                        float g = 0.5f * t * (1.f + tanhf(0.7978845608f * (t + 0.044715f * t * t * t)));
                        outb[(size_t)row * Nc + col] = f2b(g);
                    } else {
                        resout[(size_t)row * Nc + col] += val + bias[col];
                    }
                }
            }
        }
    }
}

// ---------------- compressed branch + top-8 bitmask: one wave per query ----------------
__global__ void __launch_bounds__(256) cmp_kernel(
    const u16* __restrict__ qb, const float* __restrict__ kc, const float* __restrict__ vc,
    float* __restrict__ occ, unsigned int* __restrict__ bmask)
{
    __shared__ float qs[4][64];
    const int wid = threadIdx.x >> 6;
    const int lane = threadIdx.x & 63;
    int qi = blockIdx.x * 4 + wid;          // 0..32767 = bh*1024 + n
    int bh = qi >> 10;
    qs[wid][lane] = b2f(qb[(size_t)qi * 64 + lane]);
    __syncthreads();
    const float* qsw = qs[wid];
    const float* kcs = kc + (size_t)bh * 2048;
    const float* vcs = vc + (size_t)bh * 2048;
    const int m = lane & 31, half = lane >> 5;
    float part = 0.f;
    {
        const float* kr = kcs + m * 64 + half * 32;
        const float* qh = qsw + half * 32;
        #pragma unroll
        for (int i2 = 0; i2 < 8; ++i2) {
            f32x4 kv = *(const f32x4*)(kr + i2 * 4);
            f32x4 qv = *(const f32x4*)(qh + i2 * 4);
            part += qv[0] * kv[0] + qv[1] * kv[1] + qv[2] * kv[2] + qv[3] * kv[3];
        }
    }
    float sc = part + __shfl_xor(part, 32);
    float mxc = sc;
    #pragma unroll
    for (int d = 1; d < 32; d <<= 1) mxc = fmaxf(mxc, __shfl_xor(mxc, d));
    float pc = __expf(sc - mxc);
    float denc = pc;
    #pragma unroll
    for (int d = 1; d < 32; d <<= 1) denc += __shfl_xor(denc, d);
    float oc = 0.f;
    #pragma unroll 4
    for (int mm = 0; mm < 32; ++mm) {
        float p = __shfl(pc, mm);
        oc += p * vcs[mm * 64 + lane];
    }
    oc /= denc;

    int sel[8];
    float cur = sc;
    #pragma unroll
    for (int t = 0; t < 8; ++t) {
        float val = cur; int idx = m;
        #pragma unroll
        for (int d = 1; d < 32; d <<= 1) {
            float ovv = __shfl_xor(val, d);
            int oi = __shfl_xor(idx, d);
            if (ovv > val || (ovv == val && oi < idx)) { val = ovv; idx = oi; }
        }
        sel[t] = idx;
        if (m == idx) cur = -3.4e38f;
    }
    unsigned bits = 0;
    #pragma unroll
    for (int t = 0; t < 8; ++t) bits |= 1u << sel[t];
    occ[(size_t)qi * 64 + lane] = oc;
    if (lane == 0) bmask[qi] = bits;
}

// ---------------- MFMA selection+window attention: one wave per 32-query tile ----------------
__global__ void __launch_bounds__(256) attn_mfma(
    const u16* __restrict__ qb, const u16* __restrict__ kb, const u16* __restrict__ vt,
    const float* __restrict__ occ, const unsigned int* __restrict__ bmask,
    const float* __restrict__ gates, u16* __restrict__ att)
{
    __shared__ u16 Ps[4][32][40];
    __shared__ u16 Pw[4][32][40];
    const int tid = threadIdx.x, wid = tid >> 6, lane = tid & 63;
    const int qc = lane & 31, hi = lane >> 5;
    const int g = blockIdx.x;                  // 0..255
    const int xcd = g & 7, ii = g >> 3;        // ii 0..31
    const int bh = xcd * 4 + (ii >> 3);
    const int qt = ((ii & 7) << 2) + wid;      // 0..31
    const int q0 = qt << 5;
    const int qrow = q0 + qc;
    const u16* Q = qb + (size_t)bh * 65536;
    const u16* K = kb + (size_t)bh * 65536;
    const u16* V = vt + (size_t)bh * 65536;
    short8 qf[4];
    #pragma unroll
    for (int ks = 0; ks < 4; ++ks)
        qf[ks] = *(const short8*)&Q[(size_t)qrow * 64 + ks * 16 + hi * 8];
    const unsigned mask = bmask[bh * 1024 + qrow];
    const int b = bh >> 3, h = bh & 7;
    const float* grow = gates + (size_t)(b * 1024 + qrow) * 24 + h * 3;
    const float g0 = grow[0], g1 = grow[1], g2 = grow[2];
    f32x16 aS0 = {}, aS1 = {}, aW0 = {}, aW1 = {};
    float denS = 0.f, denW = 0.f;
    const int sw = (qc & 3) << 3;
    u16* PsW = &Ps[wid][qc][0];
    u16* PwW = &Pw[wid][qc][0];
    const int wlo = qt > 0 ? qt - 1 : 0;
    const int whi = qt < 31 ? qt + 1 : 31;

    for (int blk = 0; blk < 32; ++blk) {
        short8 kf[4];
        #pragma unroll
        for (int ks = 0; ks < 4; ++ks)
            kf[ks] = *(const short8*)&K[(size_t)(blk * 32 + qc) * 64 + ks * 16 + hi * 8];
        f32x16 s = {};
        #pragma unroll
        for (int ks = 0; ks < 4; ++ks)
            s = MFMA32(kf[ks], qf[ks], s);
        float e[16];
        #pragma unroll
        for (int r = 0; r < 16; ++r) e[r] = __expf(s[r]);
        const bool selb = (mask >> blk) & 1u;
        if (__ballot(selb)) {
            #pragma unroll
            for (int c4 = 0; c4 < 4; ++c4) {
                s16x4 pk;
                #pragma unroll
                for (int j = 0; j < 4; ++j)
                    pk[j] = selb ? (short)f2b(e[c4 * 4 + j]) : (short)0;
                *(s16x4*)&PsW[(c4 * 8 + hi * 4) ^ sw] = pk;
            }
            if (selb) {
                float t = 0.f;
                #pragma unroll
                for (int r = 0; r < 16; ++r) t += e[r];
                denS += t;
            }
            short8 pb0 = *(const short8*)&PsW[(hi * 8) ^ sw];
            short8 pb1 = *(const short8*)&PsW[(16 + hi * 8) ^ sw];
            const u16* Vb = V + blk * 32 + hi * 8;
            short8 v00 = *(const short8*)&Vb[(size_t)qc * NSEQ];
            short8 v01 = *(const short8*)&Vb[(size_t)qc * NSEQ + 16];
            short8 v10 = *(const short8*)&Vb[(size_t)(32 + qc) * NSEQ];
            short8 v11 = *(const short8*)&Vb[(size_t)(32 + qc) * NSEQ + 16];
            aS0 = MFMA32(v00, pb0, aS0);
            aS0 = MFMA32(v01, pb1, aS0);
            aS1 = MFMA32(v10, pb0, aS1);
            aS1 = MFMA32(v11, pb1, aS1);
        }
        if (blk >= wlo && blk <= whi) {
            float t = 0.f;
            #pragma unroll
            for (int c4 = 0; c4 < 4; ++c4) {
                s16x4 pk;
                #pragma unroll
                for (int j = 0; j < 4; ++j) {
                    int kr = j + c4 * 8 + hi * 4;
                    int dd = blk * 32 + kr - qrow;
                    float p = (dd >= -32 && dd <= 32) ? e[c4 * 4 + j] : 0.f;
                    t += p;
                    pk[j] = (short)f2b(p);
                }
                *(s16x4*)&PwW[(c4 * 8 + hi * 4) ^ sw] = pk;
            }
            denW += t;
            short8 pb0 = *(const short8*)&PwW[(hi * 8) ^ sw];
            short8 pb1 = *(const short8*)&PwW[(16 + hi * 8) ^ sw];
            const u16* Vb = V + blk * 32 + hi * 8;
            short8 v00 = *(const short8*)&Vb[(size_t)qc * NSEQ];
            short8 v01 = *(const short8*)&Vb[(size_t)qc * NSEQ + 16];
            short8 v10 = *(const short8*)&Vb[(size_t)(32 + qc) * NSEQ];
            short8 v11 = *(const short8*)&Vb[(size_t)(32 + qc) * NSEQ + 16];
            aW0 = MFMA32(v00, pb0, aW0);
            aW0 = MFMA32(v01, pb1, aW0);
            aW1 = MFMA32(v10, pb0, aW1);
            aW1 = MFMA32(v11, pb1, aW1);
        }
    }
    denS += __shfl_xor(denS, 32);
    denW += __shfl_xor(denW, 32);
    const float rs = g1 / denS, rw = g2 / denW;
    const float* ocp = occ + (size_t)(bh * 1024 + qrow) * 64;
    u16* op = att + (size_t)(b * 1024 + qrow) * NDIM + h * 64;
    #pragma unroll
    for (int c4 = 0; c4 < 4; ++c4) {
        int d0 = c4 * 8 + hi * 4;
        f32x4 o0 = *(const f32x4*)&ocp[d0];
        f32x4 o1 = *(const f32x4*)&ocp[d0 + 32];
        s16x4 w0, w1;
        #pragma unroll
        for (int j = 0; j < 4; ++j) {
            w0[j] = (short)f2b(g0 * o0[j] + rs * aS0[c4 * 4 + j] + rw * aW0[c4 * 4 + j]);
            w1[j] = (short)f2b(g0 * o1[j] + rs * aS1[c4 * 4 + j] + rw * aW1[c4 * 4 + j]);
        }
        *(s16x4*)&op[d0] = w0;
        *(s16x4*)&op[d0 + 32] = w1;
    }
}

// ---------------- host ----------------
extern "C" void kernel_launch(void* const* d_in, const int* in_sizes, int n_in,
                              void* d_out, int out_size, void* d_ws, size_t ws_size,
                              hipStream_t stream)
{
    const float* x0    = (const float*)d_in[0];
    const float* ln1_g = (const float*)d_in[1];
    const float* ln1_b = (const float*)d_in[2];
    const float* Wq    = (const float*)d_in[3];
    const float* Wk    = (const float*)d_in[4];
    const float* Wv    = (const float*)d_in[5];
    const float* Wg    = (const float*)d_in[6];
    const float* bg    = (const float*)d_in[7];
    const float* Wo    = (const float*)d_in[8];
    const float* bo    = (const float*)d_in[9];
    const float* ln2_g = (const float*)d_in[10];
    const float* ln2_b = (const float*)d_in[11];
    const float* W1    = (const float*)d_in[12];
    const float* b1    = (const float*)d_in[13];
    const float* W2    = (const float*)d_in[14];
    const float* b2    = (const float*)d_in[15];
    float* xo = (float*)d_out;

    char* w = (char*)d_ws;
    auto alloc = [&](size_t bytes) { char* p = w; w += (bytes + 255) & ~(size_t)255; return p; };
    u16*   hbf   = (u16*)  alloc((size_t)NROWS * NDIM * 2);       // 4MB
    u16*   qb    = (u16*)  alloc((size_t)NBH * NSEQ * NDH * 2);   // 4MB
    u16*   kb    = (u16*)  alloc((size_t)NBH * NSEQ * NDH * 2);   // 4MB
    u16*   vt    = (u16*)  alloc((size_t)NBH * NDH * NSEQ * 2);   // 4MB
    float* occ   = (float*)alloc((size_t)NBH * NSEQ * NDH * 4);   // 8MB
    unsigned int* bmask = (unsigned int*)alloc((size_t)NBH * NSEQ * 4);
    u16*   att   = (u16*)  alloc((size_t)NROWS * NDIM * 2);
    float* gates = (float*)alloc((size_t)NROWS * NHEAD * 3 * 4);
    float* kc    = (float*)alloc((size_t)NBH * NBLKC * NDH * 4);
    float* vc    = (float*)alloc((size_t)NBH * NBLKC * NDH * 4);
    u16*   wqkvT = (u16*)  alloc((size_t)2 * 1536 * 512 * 2);
    u16*   woT   = (u16*)  alloc((size_t)2 * 512 * 512 * 2);
    u16*   w1T   = (u16*)  alloc((size_t)2 * 2048 * 512 * 2);
    u16*   w2T   = (u16*)  alloc((size_t)2 * 512 * 2048 * 2);
    u16*   mid   = (u16*)qb;  // alias: qb/kb/vt/occ (20MB) dead during MLP; mid needs 16MB

    hipMemcpyAsync(xo, x0, (size_t)NROWS * NDIM * 4, hipMemcpyDeviceToDevice, stream);

    for (int l = 0; l < 2; ++l) {
        transpose_w<<<dim3(16, 16), 256, 0, stream>>>(Wq + (size_t)l * 512 * 512, wqkvT + (size_t)l * 1536 * 512,              512, 512);
        transpose_w<<<dim3(16, 16), 256, 0, stream>>>(Wk + (size_t)l * 512 * 512, wqkvT + (size_t)l * 1536 * 512 + 512 * 512,  512, 512);
        transpose_w<<<dim3(16, 16), 256, 0, stream>>>(Wv + (size_t)l * 512 * 512, wqkvT + (size_t)l * 1536 * 512 + 1024 * 512, 512, 512);
        transpose_w<<<dim3(16, 16), 256, 0, stream>>>(Wo + (size_t)l * 512 * 512, woT + (size_t)l * 512 * 512,                 512, 512);
        transpose_w<<<dim3(64, 16), 256, 0, stream>>>(W1 + (size_t)l * 512 * 2048, w1T + (size_t)l * 2048 * 512,               512, 2048);
        transpose_w<<<dim3(16, 64), 256, 0, stream>>>(W2 + (size_t)l * 2048 * 512, w2T + (size_t)l * 512 * 2048,               2048, 512);
    }

    for (int l = 0; l < 2; ++l) {
        ln_kernel<<<NROWS / 4, 256, 0, stream>>>(xo, ln1_g + l * NDIM, ln1_b + l * NDIM, hbf);
        gates_kernel<<<NROWS / 4, 256, 0, stream>>>(hbf, Wg + (size_t)l * NDIM * 24, bg + l * 24, gates);
        gemm_k<128, 128, EP_QKV><<<dim3(1536 / 128, NROWS / 128), 256, 0, stream>>>(
            hbf, wqkvT + (size_t)l * 1536 * 512, NROWS, 1536, 512,
            nullptr, nullptr, nullptr, qb, kb, vt);
        pool_kernel<<<(NBH * NBLKC * NDH) / 256, 256, 0, stream>>>(kb, vt, kc, vc);
        cmp_kernel<<<NBH * NSEQ / 4, 256, 0, stream>>>(qb, kc, vc, occ, bmask);
        attn_mfma<<<256, 256, 0, stream>>>(qb, kb, vt, occ, bmask, gates, att);
        gemm_k<64, 64, EP_RES><<<dim3(512 / 64, NROWS / 64), 256, 0, stream>>>(
            att, woT + (size_t)l * 512 * 512, NROWS, 512, 512,
            bo + l * NDIM, xo, nullptr, nullptr, nullptr, nullptr);
        ln_kernel<<<NROWS / 4, 256, 0, stream>>>(xo, ln2_g + l * NDIM, ln2_b + l * NDIM, hbf);
        gemm_k<128, 128, EP_GELU><<<dim3(2048 / 128, NROWS / 128), 256, 0, stream>>>(
            hbf, w1T + (size_t)l * 2048 * 512, NROWS, 2048, 512,
            b1 + l * NMLP, nullptr, mid, nullptr, nullptr, nullptr);
        gemm_k<64, 64, EP_RES><<<dim3(512 / 64, NROWS / 64), 256, 0, stream>>>(
            mid, w2T + (size_t)l * 512 * 2048, NROWS, 512, 2048,
            b2 + l * NDIM, xo, nullptr, nullptr, nullptr, nullptr);
    }
}

// Round 4
// 408.100 us; speedup vs baseline: 9.6381x; 1.2904x over previous
//
#include <hip/hip_runtime.h>
#include <cstdint>
#include <cstddef>

typedef __attribute__((ext_vector_type(4))) float f32x4;
typedef __attribute__((ext_vector_type(16))) float f32x16;
typedef __attribute__((ext_vector_type(8))) short short8;
typedef __attribute__((ext_vector_type(4))) short s16x4;
typedef unsigned short u16;
typedef unsigned long long u64;

#define DEVINL static __device__ __forceinline__
#define MFMA32(A,B,C) __builtin_amdgcn_mfma_f32_32x32x16_bf16(A,B,C,0,0,0)

constexpr int NBATCH = 4;
constexpr int NSEQ   = 1024;
constexpr int NDIM   = 512;
constexpr int NHEAD  = 8;
constexpr int NDH    = 64;
constexpr int NMLP   = 2048;
constexpr int NROWS  = NBATCH * NSEQ;   // 4096
constexpr int NBLKC  = 32;
constexpr int NBH    = NBATCH * NHEAD;  // 32

DEVINL float b2f(u16 u) { union { unsigned u; float f; } x; x.u = ((unsigned)u) << 16; return x.f; }
DEVINL u16 f2b(float v) {
    union { float f; unsigned u; } x; x.f = v;
    unsigned r = x.u + 0x7fff + ((x.u >> 16) & 1);
    return (u16)(r >> 16);
}

// ---------------- LayerNorm -> bf16 ----------------
__global__ void __launch_bounds__(256) ln_kernel(const float* __restrict__ x,
    const float* __restrict__ gg, const float* __restrict__ bb, u16* __restrict__ out)
{
    int row = blockIdx.x * 4 + (threadIdx.x >> 6);
    int lane = threadIdx.x & 63;
    const float* xr = x + (size_t)row * NDIM + lane * 8;
    f32x4 a = *(const f32x4*)xr;
    f32x4 c = *(const f32x4*)(xr + 4);
    float xv[8] = { a[0], a[1], a[2], a[3], c[0], c[1], c[2], c[3] };
    float s = 0.f, s2 = 0.f;
    #pragma unroll
    for (int i = 0; i < 8; ++i) { s += xv[i]; s2 += xv[i] * xv[i]; }
    #pragma unroll
    for (int d = 1; d < 64; d <<= 1) { s += __shfl_xor(s, d); s2 += __shfl_xor(s2, d); }
    float mean = s * (1.f / NDIM);
    float var = s2 * (1.f / NDIM) - mean * mean;
    float rstd = rsqrtf(var + 1e-5f);
    const float* gp = gg + lane * 8;
    const float* bp = bb + lane * 8;
    short8 o;
    #pragma unroll
    for (int i = 0; i < 8; ++i)
        o[i] = (short)f2b((xv[i] - mean) * rstd * gp[i] + bp[i]);
    *(short8*)(out + (size_t)row * NDIM + lane * 8) = o;
}

// ---------------- weight transpose fp32[K][Nc] -> bf16[Nc][K] ----------------
__global__ void __launch_bounds__(256) transpose_w(const float* __restrict__ W,
    u16* __restrict__ WT, int K, int Nc)
{
    __shared__ float tile[32][33];
    int tx = threadIdx.x & 31;
    int ty = threadIdx.x >> 5;
    int n0 = blockIdx.x * 32, k0 = blockIdx.y * 32;
    #pragma unroll
    for (int r = 0; r < 4; ++r) {
        int kr = ty * 4 + r;
        tile[kr][tx] = W[(size_t)(k0 + kr) * Nc + n0 + tx];
    }
    __syncthreads();
    #pragma unroll
    for (int r = 0; r < 4; ++r) {
        int nr = ty * 4 + r;
        WT[(size_t)(n0 + nr) * K + k0 + tx] = f2b(tile[tx][nr]);
    }
}

// ---------------- gates = sigmoid(h @ Wg + bg): one wave per row ----------------
__global__ void __launch_bounds__(256) gates_kernel(const u16* __restrict__ h,
    const float* __restrict__ Wg, const float* __restrict__ bg, float* __restrict__ gates)
{
    int wid = threadIdx.x >> 6, lane = threadIdx.x & 63;
    int row = blockIdx.x * 4 + wid;
    short8 hv = *(const short8*)(h + (size_t)row * NDIM + lane * 8);
    float acc[24];
    #pragma unroll
    for (int c = 0; c < 24; ++c) acc[c] = 0.f;
    const float* wg = Wg + (size_t)(lane * 8) * 24;
    #pragma unroll
    for (int j = 0; j < 8; ++j) {
        float hj = b2f((u16)hv[j]);
        const float* wr = wg + j * 24;
        #pragma unroll
        for (int c = 0; c < 24; ++c) acc[c] += hj * wr[c];
    }
    #pragma unroll
    for (int d = 1; d < 64; d <<= 1) {
        #pragma unroll
        for (int c = 0; c < 24; ++c) acc[c] += __shfl_xor(acc[c], d);
    }
    float v = 0.f;
    #pragma unroll
    for (int c = 0; c < 24; ++c) if (lane == c) v = acc[c];
    if (lane < 24)
        gates[(size_t)row * 24 + lane] = 1.f / (1.f + __expf(-(v + bg[lane])));
}

// ---------------- block mean-pool of K/V -> bf16 kc16[m][d], vct16[d][m] ----------------
__global__ void __launch_bounds__(256) pool_kernel(const u16* __restrict__ kb,
    const u16* __restrict__ vt, u16* __restrict__ kc16, u16* __restrict__ vct16)
{
    int idx = blockIdx.x * 256 + threadIdx.x; // 65536
    int d = idx & 63, m = (idx >> 6) & 31, bh = idx >> 11;
    const u16* kp = kb + ((size_t)bh * NSEQ + m * 32) * NDH + d;
    float sk = 0.f;
    #pragma unroll 8
    for (int j = 0; j < 32; ++j) sk += b2f(kp[j * NDH]);
    const u16* vp = vt + (size_t)bh * 65536 + (size_t)d * NSEQ + m * 32;
    float sv = 0.f;
    #pragma unroll 8
    for (int j = 0; j < 32; ++j) sv += b2f(vp[j]);
    kc16[(size_t)bh * 2048 + m * 64 + d] = f2b(sk * (1.f / 32.f));
    vct16[(size_t)bh * 2048 + d * 32 + m] = f2b(sv * (1.f / 32.f));
}

// ---------------- bf16 MFMA GEMM: C = A[M,K] @ (BT[Nc,K])^T ----------------
enum { EP_QKV = 0, EP_GELU = 1, EP_RES = 2 };

template<int BM, int BN, int EPIL>
__global__ void __launch_bounds__(256) gemm_k(
    const u16* __restrict__ A, const u16* __restrict__ BT,
    int M, int Nc, int K,
    const float* __restrict__ bias,
    float* __restrict__ resout,
    u16* __restrict__ outb,
    u16* __restrict__ q16, u16* __restrict__ k16, u16* __restrict__ vt16)
{
    constexpr int BK = 32;
    constexpr int WM = BM / 2, WN = BN / 2;
    constexpr int MI = WM / 16, NI = WN / 16;
    __shared__ u16 As[BM][BK + 8];
    __shared__ u16 Bs[BN][BK + 8];
    const int tid = threadIdx.x;
    const int lane = tid & 63;
    const int wid = tid >> 6;
    const int wm = wid >> 1, wn = wid & 1;
    const int rowBase = blockIdx.y * BM;
    const int colBase = blockIdx.x * BN;
    const int fr = lane & 15;
    const int kg = lane >> 4;
    const int sr = tid >> 2;
    const int sk = (tid & 3) * 8;
    f32x4 acc[MI][NI] = {};

    for (int k0 = 0; k0 < K; k0 += BK) {
        __syncthreads();
        #pragma unroll
        for (int c = 0; c < BM / 64; ++c) {
            int r = c * 64 + sr;
            *(f32x4*)(&As[r][sk]) = *(const f32x4*)(&A[(size_t)(rowBase + r) * K + k0 + sk]);
        }
        #pragma unroll
        for (int c = 0; c < BN / 64; ++c) {
            int r = c * 64 + sr;
            *(f32x4*)(&Bs[r][sk]) = *(const f32x4*)(&BT[(size_t)(colBase + r) * K + k0 + sk]);
        }
        __syncthreads();
        short8 af[MI], bfr[NI];
        #pragma unroll
        for (int i = 0; i < MI; ++i)
            af[i] = *(const short8*)(&As[wm * WM + i * 16 + fr][kg * 8]);
        #pragma unroll
        for (int j = 0; j < NI; ++j)
            bfr[j] = *(const short8*)(&Bs[wn * WN + j * 16 + fr][kg * 8]);
        #pragma unroll
        for (int i = 0; i < MI; ++i)
            #pragma unroll
            for (int j = 0; j < NI; ++j)
                acc[i][j] = __builtin_amdgcn_mfma_f32_16x16x32_bf16(af[i], bfr[j], acc[i][j], 0, 0, 0);
    }

    #pragma unroll
    for (int i = 0; i < MI; ++i) {
        #pragma unroll
        for (int j = 0; j < NI; ++j) {
            int col = colBase + wn * WN + j * 16 + fr;
            if constexpr (EPIL == EP_QKV) {
                int which = col >> 9, c = col & 511;
                int hh = c >> 6, dh = c & 63;
                int row0 = rowBase + wm * WM + i * 16 + kg * 4;
                int bb2 = row0 >> 10, n0 = row0 & 1023;
                size_t bh2 = (size_t)(bb2 * NHEAD + hh) * 65536;
                if (which == 2) {
                    s16x4 pk;
                    #pragma unroll
                    for (int rr = 0; rr < 4; ++rr) pk[rr] = (short)f2b(acc[i][j][rr]);
                    *(s16x4*)&vt16[bh2 + (size_t)dh * NSEQ + n0] = pk;
                } else {
                    u16* dst = (which ? k16 : q16) + bh2 + (size_t)n0 * NDH + dh;
                    float scl = which ? 1.f : 0.125f;
                    #pragma unroll
                    for (int rr = 0; rr < 4; ++rr) dst[rr * NDH] = f2b(acc[i][j][rr] * scl);
                }
            } else {
                #pragma unroll
                for (int rr = 0; rr < 4; ++rr) {
                    int row = rowBase + wm * WM + i * 16 + kg * 4 + rr;
                    float val = acc[i][j][rr];
                    if constexpr (EPIL == EP_GELU) {
                        float t = val + bias[col];
                        float g = 0.5f * t * (1.f + tanhf(0.7978845608f * (t + 0.044715f * t * t * t)));
                        outb[(size_t)row * Nc + col] = f2b(g);
                    } else {
                        resout[(size_t)row * Nc + col] += val + bias[col];
                    }
                }
            }
        }
    }
}

// monotone float -> ordered uint
DEVINL unsigned ordf(float f)
{
    union { float f; unsigned u; } x; x.f = f;
    unsigned m_ = ((int)x.u >> 31) | 0x80000000u;
    return x.u ^ m_;
}

// ---------------- MFMA attention (all 3 branches): one wave per 32-query tile ----------------
__global__ void __launch_bounds__(256) attn_mfma(
    const u16* __restrict__ qb, const u16* __restrict__ kb, const u16* __restrict__ vt,
    const u16* __restrict__ kc16, const u16* __restrict__ vct16,
    const float* __restrict__ gates, u16* __restrict__ att)
{
    __shared__ u16 Ps[4][32][40];
    __shared__ u16 Pw[4][32][40];
    const int tid = threadIdx.x, wid = tid >> 6, lane = tid & 63;
    const int qc = lane & 31, hi = lane >> 5;
    const int g = blockIdx.x;                  // 0..255
    const int xcd = g & 7, ii = g >> 3;        // ii 0..31
    const int bh = xcd * 4 + (ii >> 3);
    const int qt = ((ii & 7) << 2) + wid;      // 0..31
    const int q0 = qt << 5;
    const int qrow = q0 + qc;
    const u16* Q = qb + (size_t)bh * 65536;
    const u16* K = kb + (size_t)bh * 65536;
    const u16* V = vt + (size_t)bh * 65536;
    short8 qf[4];
    #pragma unroll
    for (int ks = 0; ks < 4; ++ks)
        qf[ks] = *(const short8*)&Q[(size_t)qrow * 64 + ks * 16 + hi * 8];
    const int b = bh >> 3, h = bh & 7;
    const float* grow = gates + (size_t)(b * 1024 + qrow) * 24 + h * 3;
    const float g0 = grow[0], g1 = grow[1], g2 = grow[2];
    const int sw = (qc & 3) << 3;
    u16* PsW = &Ps[wid][qc][0];
    u16* PwW = &Pw[wid][qc][0];

    // ================= compressed branch + top-8 bitmask =================
    const u16* Kc = kc16 + (size_t)bh * 2048;   // [m][d]
    const u16* Vc = vct16 + (size_t)bh * 2048;  // [d][m]
    f32x16 sc_ = {};
    #pragma unroll
    for (int ks = 0; ks < 4; ++ks) {
        short8 kcf = *(const short8*)&Kc[qc * 64 + ks * 16 + hi * 8];
        sc_ = MFMA32(kcf, qf[ks], sc_);
    }
    float ec[16], denc = 0.f;
    #pragma unroll
    for (int r = 0; r < 16; ++r) { ec[r] = __expf(sc_[r]); denc += ec[r]; }
    denc += __shfl_xor(denc, 32);

    // ordered keys: (monotone score bits << 5) | (31 - blockidx); rank<8 => selected
    u64 keys[32];
    #pragma unroll
    for (int r = 0; r < 16; ++r) {
        int base = (r & 3) + 8 * (r >> 2);
        keys[r] = ((u64)ordf(sc_[r]) << 5) | (unsigned)(31 - (base + 4 * hi));
        float po = __shfl_xor(sc_[r], 32);
        keys[16 + r] = ((u64)ordf(po) << 5) | (unsigned)(31 - (base + 4 - 4 * hi));
    }
    unsigned bits = 0;
    #pragma unroll
    for (int r = 0; r < 16; ++r) {
        int cnt = 0;
        #pragma unroll
        for (int j = 0; j < 32; ++j) cnt += (keys[j] > keys[r]) ? 1 : 0;
        if (cnt < 8) bits |= 1u << ((r & 3) + 8 * (r >> 2) + 4 * hi);
    }
    const unsigned mask = bits | __shfl_xor(bits, 32);

    // compressed PV via LDS staging (same layout identity as selection path)
    f32x16 acC0 = {}, acC1 = {};
    {
        #pragma unroll
        for (int c4 = 0; c4 < 4; ++c4) {
            s16x4 pk;
            #pragma unroll
            for (int j = 0; j < 4; ++j) pk[j] = (short)f2b(ec[c4 * 4 + j]);
            *(s16x4*)&PsW[(c4 * 8 + hi * 4) ^ sw] = pk;
        }
        short8 pb0 = *(const short8*)&PsW[(hi * 8) ^ sw];
        short8 pb1 = *(const short8*)&PsW[(16 + hi * 8) ^ sw];
        short8 vc00 = *(const short8*)&Vc[qc * 32 + hi * 8];
        short8 vc01 = *(const short8*)&Vc[qc * 32 + 16 + hi * 8];
        short8 vc10 = *(const short8*)&Vc[(32 + qc) * 32 + hi * 8];
        short8 vc11 = *(const short8*)&Vc[(32 + qc) * 32 + 16 + hi * 8];
        acC0 = MFMA32(vc00, pb0, acC0);
        acC0 = MFMA32(vc01, pb1, acC0);
        acC1 = MFMA32(vc10, pb0, acC1);
        acC1 = MFMA32(vc11, pb1, acC1);
    }

    // ================= selection + window branches =================
    f32x16 aS0 = {}, aS1 = {}, aW0 = {}, aW1 = {};
    float denS = 0.f, denW = 0.f;
    const int wlo = qt > 0 ? qt - 1 : 0;
    const int whi = qt < 31 ? qt + 1 : 31;

    for (int blk = 0; blk < 32; ++blk) {
        short8 kf[4];
        #pragma unroll
        for (int ks = 0; ks < 4; ++ks)
            kf[ks] = *(const short8*)&K[(size_t)(blk * 32 + qc) * 64 + ks * 16 + hi * 8];
        f32x16 s = {};
        #pragma unroll
        for (int ks = 0; ks < 4; ++ks)
            s = MFMA32(kf[ks], qf[ks], s);
        float e[16];
        #pragma unroll
        for (int r = 0; r < 16; ++r) e[r] = __expf(s[r]);
        const bool selb = (mask >> blk) & 1u;
        if (__ballot(selb)) {
            #pragma unroll
            for (int c4 = 0; c4 < 4; ++c4) {
                s16x4 pk;
                #pragma unroll
                for (int j = 0; j < 4; ++j)
                    pk[j] = selb ? (short)f2b(e[c4 * 4 + j]) : (short)0;
                *(s16x4*)&PsW[(c4 * 8 + hi * 4) ^ sw] = pk;
            }
            if (selb) {
                float t = 0.f;
                #pragma unroll
                for (int r = 0; r < 16; ++r) t += e[r];
                denS += t;
            }
            short8 pb0 = *(const short8*)&PsW[(hi * 8) ^ sw];
            short8 pb1 = *(const short8*)&PsW[(16 + hi * 8) ^ sw];
            const u16* Vb = V + blk * 32 + hi * 8;
            short8 v00 = *(const short8*)&Vb[(size_t)qc * NSEQ];
            short8 v01 = *(const short8*)&Vb[(size_t)qc * NSEQ + 16];
            short8 v10 = *(const short8*)&Vb[(size_t)(32 + qc) * NSEQ];
            short8 v11 = *(const short8*)&Vb[(size_t)(32 + qc) * NSEQ + 16];
            aS0 = MFMA32(v00, pb0, aS0);
            aS0 = MFMA32(v01, pb1, aS0);
            aS1 = MFMA32(v10, pb0, aS1);
            aS1 = MFMA32(v11, pb1, aS1);
        }
        if (blk >= wlo && blk <= whi) {
            float t = 0.f;
            #pragma unroll
            for (int c4 = 0; c4 < 4; ++c4) {
                s16x4 pk;
                #pragma unroll
                for (int j = 0; j < 4; ++j) {
                    int kr = j + c4 * 8 + hi * 4;
                    int dd = blk * 32 + kr - qrow;
                    float p = (dd >= -32 && dd <= 32) ? e[c4 * 4 + j] : 0.f;
                    t += p;
                    pk[j] = (short)f2b(p);
                }
                *(s16x4*)&PwW[(c4 * 8 + hi * 4) ^ sw] = pk;
            }
            denW += t;
            short8 pb0 = *(const short8*)&PwW[(hi * 8) ^ sw];
            short8 pb1 = *(const short8*)&PwW[(16 + hi * 8) ^ sw];
            const u16* Vb = V + blk * 32 + hi * 8;
            short8 v00 = *(const short8*)&Vb[(size_t)qc * NSEQ];
            short8 v01 = *(const short8*)&Vb[(size_t)qc * NSEQ + 16];
            short8 v10 = *(const short8*)&Vb[(size_t)(32 + qc) * NSEQ];
            short8 v11 = *(const short8*)&Vb[(size_t)(32 + qc) * NSEQ + 16];
            aW0 = MFMA32(v00, pb0, aW0);
            aW0 = MFMA32(v01, pb1, aW0);
            aW1 = MFMA32(v10, pb0, aW1);
            aW1 = MFMA32(v11, pb1, aW1);
        }
    }
    denS += __shfl_xor(denS, 32);
    denW += __shfl_xor(denW, 32);
    const float rc = g0 / denc, rs = g1 / denS, rw = g2 / denW;
    u16* op = att + (size_t)(b * 1024 + qrow) * NDIM + h * 64;
    #pragma unroll
    for (int c4 = 0; c4 < 4; ++c4) {
        int d0 = c4 * 8 + hi * 4;
        s16x4 w0, w1;
        #pragma unroll
        for (int j = 0; j < 4; ++j) {
            w0[j] = (short)f2b(rc * acC0[c4 * 4 + j] + rs * aS0[c4 * 4 + j] + rw * aW0[c4 * 4 + j]);
            w1[j] = (short)f2b(rc * acC1[c4 * 4 + j] + rs * aS1[c4 * 4 + j] + rw * aW1[c4 * 4 + j]);
        }
        *(s16x4*)&op[d0] = w0;
        *(s16x4*)&op[d0 + 32] = w1;
    }
}

// ---------------- host ----------------
extern "C" void kernel_launch(void* const* d_in, const int* in_sizes, int n_in,
                              void* d_out, int out_size, void* d_ws, size_t ws_size,
                              hipStream_t stream)
{
    const float* x0    = (const float*)d_in[0];
    const float* ln1_g = (const float*)d_in[1];
    const float* ln1_b = (const float*)d_in[2];
    const float* Wq    = (const float*)d_in[3];
    const float* Wk    = (const float*)d_in[4];
    const float* Wv    = (const float*)d_in[5];
    const float* Wg    = (const float*)d_in[6];
    const float* bg    = (const float*)d_in[7];
    const float* Wo    = (const float*)d_in[8];
    const float* bo    = (const float*)d_in[9];
    const float* ln2_g = (const float*)d_in[10];
    const float* ln2_b = (const float*)d_in[11];
    const float* W1    = (const float*)d_in[12];
    const float* b1    = (const float*)d_in[13];
    const float* W2    = (const float*)d_in[14];
    const float* b2    = (const float*)d_in[15];
    float* xo = (float*)d_out;

    char* w = (char*)d_ws;
    auto alloc = [&](size_t bytes) { char* p = w; w += (bytes + 255) & ~(size_t)255; return p; };
    u16*   hbf   = (u16*)  alloc((size_t)NROWS * NDIM * 2);       // 4MB
    u16*   qb    = (u16*)  alloc((size_t)NBH * NSEQ * NDH * 2);   // 4MB
    u16*   kb    = (u16*)  alloc((size_t)NBH * NSEQ * NDH * 2);   // 4MB
    u16*   vt    = (u16*)  alloc((size_t)NBH * NDH * NSEQ * 2);   // 4MB
    u16*   att   = (u16*)  alloc((size_t)NROWS * NDIM * 2);       // 4MB
    float* gates = (float*)alloc((size_t)NROWS * NHEAD * 3 * 4);
    u16*   kc16  = (u16*)  alloc((size_t)NBH * NBLKC * NDH * 2);
    u16*   vct16 = (u16*)  alloc((size_t)NBH * NDH * NBLKC * 2);
    u16*   wqkvT = (u16*)  alloc((size_t)2 * 1536 * 512 * 2);
    u16*   woT   = (u16*)  alloc((size_t)2 * 512 * 512 * 2);
    u16*   w1T   = (u16*)  alloc((size_t)2 * 2048 * 512 * 2);
    u16*   w2T   = (u16*)  alloc((size_t)2 * 512 * 2048 * 2);
    u16*   mid   = (u16*)qb;  // alias: qb+kb+vt+att (16MB) dead during MLP; mid needs 16MB

    hipMemcpyAsync(xo, x0, (size_t)NROWS * NDIM * 4, hipMemcpyDeviceToDevice, stream);

    for (int l = 0; l < 2; ++l) {
        transpose_w<<<dim3(16, 16), 256, 0, stream>>>(Wq + (size_t)l * 512 * 512, wqkvT + (size_t)l * 1536 * 512,              512, 512);
        transpose_w<<<dim3(16, 16), 256, 0, stream>>>(Wk + (size_t)l * 512 * 512, wqkvT + (size_t)l * 1536 * 512 + 512 * 512,  512, 512);
        transpose_w<<<dim3(16, 16), 256, 0, stream>>>(Wv + (size_t)l * 512 * 512, wqkvT + (size_t)l * 1536 * 512 + 1024 * 512, 512, 512);
        transpose_w<<<dim3(16, 16), 256, 0, stream>>>(Wo + (size_t)l * 512 * 512, woT + (size_t)l * 512 * 512,                 512, 512);
        transpose_w<<<dim3(64, 16), 256, 0, stream>>>(W1 + (size_t)l * 512 * 2048, w1T + (size_t)l * 2048 * 512,               512, 2048);
        transpose_w<<<dim3(16, 64), 256, 0, stream>>>(W2 + (size_t)l * 2048 * 512, w2T + (size_t)l * 512 * 2048,               2048, 512);
    }

    for (int l = 0; l < 2; ++l) {
        ln_kernel<<<NROWS / 4, 256, 0, stream>>>(xo, ln1_g + l * NDIM, ln1_b + l * NDIM, hbf);
        gates_kernel<<<NROWS / 4, 256, 0, stream>>>(hbf, Wg + (size_t)l * NDIM * 24, bg + l * 24, gates);
        gemm_k<128, 128, EP_QKV><<<dim3(1536 / 128, NROWS / 128), 256, 0, stream>>>(
            hbf, wqkvT + (size_t)l * 1536 * 512, NROWS, 1536, 512,
            nullptr, nullptr, nullptr, qb, kb, vt);
        pool_kernel<<<(NBH * NBLKC * NDH) / 256, 256, 0, stream>>>(kb, vt, kc16, vct16);
        attn_mfma<<<256, 256, 0, stream>>>(qb, kb, vt, kc16, vct16, gates, att);
        gemm_k<64, 64, EP_RES><<<dim3(512 / 64, NROWS / 64), 256, 0, stream>>>(
            att, woT + (size_t)l * 512 * 512, NROWS, 512, 512,
            bo + l * NDIM, xo, nullptr, nullptr, nullptr, nullptr);
        ln_kernel<<<NROWS / 4, 256, 0, stream>>>(xo, ln2_g + l * NDIM, ln2_b + l * NDIM, hbf);
        gemm_k<128, 128, EP_GELU><<<dim3(2048 / 128, NROWS / 128), 256, 0, stream>>>(
            hbf, w1T + (size_t)l * 2048 * 512, NROWS, 2048, 512,
            b1 + l * NMLP, nullptr, mid, nullptr, nullptr, nullptr);
        gemm_k<64, 64, EP_RES><<<dim3(512 / 64, NROWS / 64), 256, 0, stream>>>(
            mid, w2T + (size_t)l * 512 * 2048, NROWS, 512, 2048,
            b2 + l * NDIM, xo, nullptr, nullptr, nullptr, nullptr);
    }
}

// Round 5
// 401.885 us; speedup vs baseline: 9.7871x; 1.0155x over previous
//
#include <hip/hip_runtime.h>
#include <cstdint>
#include <cstddef>

typedef __attribute__((ext_vector_type(4))) float f32x4;
typedef __attribute__((ext_vector_type(16))) float f32x16;
typedef __attribute__((ext_vector_type(8))) short short8;
typedef __attribute__((ext_vector_type(4))) short s16x4;
typedef __attribute__((ext_vector_type(2))) int int2v;
typedef unsigned short u16;

#define DEVINL static __device__ __forceinline__
#define MFMA32(A,B,C) __builtin_amdgcn_mfma_f32_32x32x16_bf16(A,B,C,0,0,0)

constexpr int NBATCH = 4;
constexpr int NSEQ   = 1024;
constexpr int NDIM   = 512;
constexpr int NHEAD  = 8;
constexpr int NDH    = 64;
constexpr int NMLP   = 2048;
constexpr int NROWS  = NBATCH * NSEQ;   // 4096
constexpr int NBLKC  = 32;
constexpr int NBH    = NBATCH * NHEAD;  // 32

DEVINL float b2f(u16 u) { union { unsigned u; float f; } x; x.u = ((unsigned)u) << 16; return x.f; }
DEVINL u16 f2b(float v) {
    union { float f; unsigned u; } x; x.f = v;
    unsigned r = x.u + 0x7fff + ((x.u >> 16) & 1);
    return (u16)(r >> 16);
}

// ---------------- LayerNorm -> bf16 ----------------
__global__ void __launch_bounds__(256) ln_kernel(const float* __restrict__ x,
    const float* __restrict__ gg, const float* __restrict__ bb, u16* __restrict__ out)
{
    int row = blockIdx.x * 4 + (threadIdx.x >> 6);
    int lane = threadIdx.x & 63;
    const float* xr = x + (size_t)row * NDIM + lane * 8;
    f32x4 a = *(const f32x4*)xr;
    f32x4 c = *(const f32x4*)(xr + 4);
    float xv[8] = { a[0], a[1], a[2], a[3], c[0], c[1], c[2], c[3] };
    float s = 0.f, s2 = 0.f;
    #pragma unroll
    for (int i = 0; i < 8; ++i) { s += xv[i]; s2 += xv[i] * xv[i]; }
    #pragma unroll
    for (int d = 1; d < 64; d <<= 1) { s += __shfl_xor(s, d); s2 += __shfl_xor(s2, d); }
    float mean = s * (1.f / NDIM);
    float var = s2 * (1.f / NDIM) - mean * mean;
    float rstd = rsqrtf(var + 1e-5f);
    const float* gp = gg + lane * 8;
    const float* bp = bb + lane * 8;
    short8 o;
    #pragma unroll
    for (int i = 0; i < 8; ++i)
        o[i] = (short)f2b((xv[i] - mean) * rstd * gp[i] + bp[i]);
    *(short8*)(out + (size_t)row * NDIM + lane * 8) = o;
}

// ---------------- weight transpose fp32[K][Nc] -> bf16[Nc][K] ----------------
__global__ void __launch_bounds__(256) transpose_w(const float* __restrict__ W,
    u16* __restrict__ WT, int K, int Nc)
{
    __shared__ float tile[32][33];
    int tx = threadIdx.x & 31;
    int ty = threadIdx.x >> 5;
    int n0 = blockIdx.x * 32, k0 = blockIdx.y * 32;
    #pragma unroll
    for (int r = 0; r < 4; ++r) {
        int kr = ty * 4 + r;
        tile[kr][tx] = W[(size_t)(k0 + kr) * Nc + n0 + tx];
    }
    __syncthreads();
    #pragma unroll
    for (int r = 0; r < 4; ++r) {
        int nr = ty * 4 + r;
        WT[(size_t)(n0 + nr) * K + k0 + tx] = f2b(tile[tx][nr]);
    }
}

// ---------------- gates = sigmoid(h @ Wg + bg): one wave per row ----------------
__global__ void __launch_bounds__(256) gates_kernel(const u16* __restrict__ h,
    const float* __restrict__ Wg, const float* __restrict__ bg, float* __restrict__ gates)
{
    int wid = threadIdx.x >> 6, lane = threadIdx.x & 63;
    int row = blockIdx.x * 4 + wid;
    short8 hv = *(const short8*)(h + (size_t)row * NDIM + lane * 8);
    float acc[24];
    #pragma unroll
    for (int c = 0; c < 24; ++c) acc[c] = 0.f;
    const float* wg = Wg + (size_t)(lane * 8) * 24;
    #pragma unroll
    for (int j = 0; j < 8; ++j) {
        float hj = b2f((u16)hv[j]);
        const float* wr = wg + j * 24;
        #pragma unroll
        for (int c = 0; c < 24; ++c) acc[c] += hj * wr[c];
    }
    #pragma unroll
    for (int d = 1; d < 64; d <<= 1) {
        #pragma unroll
        for (int c = 0; c < 24; ++c) acc[c] += __shfl_xor(acc[c], d);
    }
    float v = 0.f;
    #pragma unroll
    for (int c = 0; c < 24; ++c) if (lane == c) v = acc[c];
    if (lane < 24)
        gates[(size_t)row * 24 + lane] = 1.f / (1.f + __expf(-(v + bg[lane])));
}

// ---------------- block mean-pool of K/V -> bf16 kc16[m][d], vct16[d][m] ----------------
__global__ void __launch_bounds__(256) pool_kernel(const u16* __restrict__ kb,
    const u16* __restrict__ vt, u16* __restrict__ kc16, u16* __restrict__ vct16)
{
    int idx = blockIdx.x * 256 + threadIdx.x; // 65536
    int d = idx & 63, m = (idx >> 6) & 31, bh = idx >> 11;
    const u16* kp = kb + ((size_t)bh * NSEQ + m * 32) * NDH + d;
    float sk = 0.f;
    #pragma unroll 8
    for (int j = 0; j < 32; ++j) sk += b2f(kp[j * NDH]);
    const u16* vp = vt + (size_t)bh * 65536 + (size_t)d * NSEQ + m * 32;
    float sv = 0.f;
    #pragma unroll 8
    for (int j = 0; j < 32; ++j) sv += b2f(vp[j]);
    kc16[(size_t)bh * 2048 + m * 64 + d] = f2b(sk * (1.f / 32.f));
    vct16[(size_t)bh * 2048 + d * 32 + m] = f2b(sv * (1.f / 32.f));
}

// ---------------- bf16 MFMA GEMM: C = A[M,K] @ (BT[Nc,K])^T ----------------
enum { EP_QKV = 0, EP_GELU = 1, EP_RES = 2 };

template<int BM, int BN, int EPIL>
__global__ void __launch_bounds__(256) gemm_k(
    const u16* __restrict__ A, const u16* __restrict__ BT,
    int M, int Nc, int K,
    const float* __restrict__ bias,
    float* __restrict__ resout,
    u16* __restrict__ outb,
    u16* __restrict__ q16, u16* __restrict__ k16, u16* __restrict__ vt16)
{
    constexpr int BK = 32;
    constexpr int WM = BM / 2, WN = BN / 2;
    constexpr int MI = WM / 16, NI = WN / 16;
    __shared__ u16 As[BM][BK + 8];
    __shared__ u16 Bs[BN][BK + 8];
    const int tid = threadIdx.x;
    const int lane = tid & 63;
    const int wid = tid >> 6;
    const int wm = wid >> 1, wn = wid & 1;
    const int rowBase = blockIdx.y * BM;
    const int colBase = blockIdx.x * BN;
    const int fr = lane & 15;
    const int kg = lane >> 4;
    const int sr = tid >> 2;
    const int sk = (tid & 3) * 8;
    f32x4 acc[MI][NI] = {};

    for (int k0 = 0; k0 < K; k0 += BK) {
        __syncthreads();
        #pragma unroll
        for (int c = 0; c < BM / 64; ++c) {
            int r = c * 64 + sr;
            *(f32x4*)(&As[r][sk]) = *(const f32x4*)(&A[(size_t)(rowBase + r) * K + k0 + sk]);
        }
        #pragma unroll
        for (int c = 0; c < BN / 64; ++c) {
            int r = c * 64 + sr;
            *(f32x4*)(&Bs[r][sk]) = *(const f32x4*)(&BT[(size_t)(colBase + r) * K + k0 + sk]);
        }
        __syncthreads();
        short8 af[MI], bfr[NI];
        #pragma unroll
        for (int i = 0; i < MI; ++i)
            af[i] = *(const short8*)(&As[wm * WM + i * 16 + fr][kg * 8]);
        #pragma unroll
        for (int j = 0; j < NI; ++j)
            bfr[j] = *(const short8*)(&Bs[wn * WN + j * 16 + fr][kg * 8]);
        #pragma unroll
        for (int i = 0; i < MI; ++i)
            #pragma unroll
            for (int j = 0; j < NI; ++j)
                acc[i][j] = __builtin_amdgcn_mfma_f32_16x16x32_bf16(af[i], bfr[j], acc[i][j], 0, 0, 0);
    }

    #pragma unroll
    for (int i = 0; i < MI; ++i) {
        #pragma unroll
        for (int j = 0; j < NI; ++j) {
            int col = colBase + wn * WN + j * 16 + fr;
            if constexpr (EPIL == EP_QKV) {
                int which = col >> 9, c = col & 511;
                int hh = c >> 6, dh = c & 63;
                int row0 = rowBase + wm * WM + i * 16 + kg * 4;
                int bb2 = row0 >> 10, n0 = row0 & 1023;
                size_t bh2 = (size_t)(bb2 * NHEAD + hh) * 65536;
                if (which == 2) {
                    s16x4 pk;
                    #pragma unroll
                    for (int rr = 0; rr < 4; ++rr) pk[rr] = (short)f2b(acc[i][j][rr]);
                    *(s16x4*)&vt16[bh2 + (size_t)dh * NSEQ + n0] = pk;
                } else {
                    u16* dst = (which ? k16 : q16) + bh2 + (size_t)n0 * NDH + dh;
                    float scl = which ? 1.f : 0.125f;
                    #pragma unroll
                    for (int rr = 0; rr < 4; ++rr) dst[rr * NDH] = f2b(acc[i][j][rr] * scl);
                }
            } else {
                #pragma unroll
                for (int rr = 0; rr < 4; ++rr) {
                    int row = rowBase + wm * WM + i * 16 + kg * 4 + rr;
                    float val = acc[i][j][rr];
                    if constexpr (EPIL == EP_GELU) {
                        float t = val + bias[col];
                        float g = 0.5f * t * (1.f + tanhf(0.7978845608f * (t + 0.044715f * t * t * t)));
                        outb[(size_t)row * Nc + col] = f2b(g);
                    } else {
                        resout[(size_t)row * Nc + col] += val + bias[col];
                    }
                }
            }
        }
    }
}

// pack 2 f32 -> 1 word of 2 bf16 (RNE)
DEVINL unsigned cvtpk(float lo, float hi_)
{
    unsigned t;
    asm("v_cvt_pk_bf16_f32 %0, %1, %2" : "=v"(t) : "v"(lo), "v"(hi_));
    return t;
}

DEVINL void plswap(unsigned& a, unsigned& b)
{
#if __has_builtin(__builtin_amdgcn_permlane32_swap)
    int2v r = __builtin_amdgcn_permlane32_swap((int)a, (int)b, false, false);
    a = (unsigned)r[0]; b = (unsigned)r[1];
#else
    asm("v_permlane32_swap_b32 %0, %1" : "+v"(a), "+v"(b));
#endif
}

// e[16] (QK^T C-frag scores) -> PV B-frags pb0 (k=0..15), pb1 (k=16..31).
// selmask = 0xFFFFFFFF keep / 0 zero (uniform across lane pair).
DEVINL void packswap(const float* e, unsigned selmask, short8& pb0, short8& pb1)
{
    unsigned w[8];
    #pragma unroll
    for (int i = 0; i < 8; ++i) w[i] = cvtpk(e[2 * i], e[2 * i + 1]) & selmask;
    plswap(w[0], w[2]); plswap(w[1], w[3]);
    plswap(w[4], w[6]); plswap(w[5], w[7]);
    union { unsigned u[4]; short8 s; } c0, c1;
    c0.u[0] = w[0]; c0.u[1] = w[1]; c0.u[2] = w[2]; c0.u[3] = w[3];
    c1.u[0] = w[4]; c1.u[1] = w[5]; c1.u[2] = w[6]; c1.u[3] = w[7];
    pb0 = c0.s; pb1 = c1.s;
}

// ---------------- MFMA attention: 2 waves per 32-query tile (d-split) ----------------
__global__ void __launch_bounds__(128) attn_mfma(
    const u16* __restrict__ qb, const u16* __restrict__ kb, const u16* __restrict__ vt,
    const u16* __restrict__ kc16, const u16* __restrict__ vct16,
    const float* __restrict__ gates, u16* __restrict__ att)
{
    const int tid = threadIdx.x, half = tid >> 6, lane = tid & 63;
    const int qc = lane & 31, hi = lane >> 5;
    const int g = blockIdx.x;                  // 0..1023
    const int xcd = g & 7, ii = g >> 3;        // ii 0..127
    const int bh = xcd * 4 + (ii >> 5);
    const int qt = ii & 31;
    const int qrow = qt * 32 + qc;
    const u16* Q = qb + (size_t)bh * 65536;
    const u16* K = kb + (size_t)bh * 65536;
    const u16* V = vt + (size_t)bh * 65536;
    short8 qf[4];
    #pragma unroll
    for (int ks = 0; ks < 4; ++ks)
        qf[ks] = *(const short8*)&Q[(size_t)qrow * 64 + ks * 16 + hi * 8];
    const int b = bh >> 3, h = bh & 7;
    const float* grow = gates + (size_t)(b * 1024 + qrow) * 24 + h * 3;
    const float g0 = grow[0], g1 = grow[1], g2 = grow[2];

    // ================= compressed branch + top-8 bitmask =================
    const u16* Kc = kc16 + (size_t)bh * 2048;   // [m][d]
    const u16* Vc = vct16 + (size_t)bh * 2048;  // [d][m]
    f32x16 sc_ = {};
    #pragma unroll
    for (int ks = 0; ks < 4; ++ks) {
        short8 kcf = *(const short8*)&Kc[qc * 64 + ks * 16 + hi * 8];
        sc_ = MFMA32(kcf, qf[ks], sc_);
    }
    float ec[16], denc = 0.f;
    #pragma unroll
    for (int r = 0; r < 16; ++r) { ec[r] = __expf(sc_[r]); denc += ec[r]; }
    denc += __shfl_xor(denc, 32);

    // rank per score: cnt of strictly-greater (score, then lower idx wins ties); cnt<8 => top-8
    float po[16];
    #pragma unroll
    for (int r = 0; r < 16; ++r) po[r] = __shfl_xor(sc_[r], 32);
    unsigned bits = 0;
    #pragma unroll
    for (int r = 0; r < 16; ++r) {
        const int krr = (r & 3) + 8 * (r >> 2);          // own key row (mod hi offset)
        const float sr = sc_[r];
        int cnt = 0;
        #pragma unroll
        for (int j = 0; j < 16; ++j) {
            const int krj = (j & 3) + 8 * (j >> 2);
            if (j != r) cnt += (sc_[j] > sr || (sc_[j] == sr && krj < krr)) ? 1 : 0;
            // partner's key idx = krj + 4*(1-hi); own = krr + 4*hi
            const bool pless = (hi == 0) ? (krj + 4 < krr) : (krj < krr + 4);
            cnt += (po[j] > sr || (po[j] == sr && pless)) ? 1 : 0;
        }
        if (cnt < 8) bits |= 1u << (krr + 4 * hi);
    }
    const unsigned mask = bits | __shfl_xor(bits, 32);

    // compressed PV (this wave's d-half only)
    f32x16 aC = {};
    {
        short8 pc0, pc1;
        packswap(ec, 0xFFFFFFFFu, pc0, pc1);
        const u16* Vch = Vc + (half * 32 + qc) * 32 + hi * 8;
        short8 vcA = *(const short8*)&Vch[0];
        short8 vcB = *(const short8*)&Vch[16];
        aC = MFMA32(vcA, pc0, aC);
        aC = MFMA32(vcB, pc1, aC);
    }

    // ================= selection + window branches =================
    f32x16 aS = {}, aW = {};
    float denS = 0.f, denW = 0.f;
    const int wlo = qt > 0 ? qt - 1 : 0;
    const int whi = qt < 31 ? qt + 1 : 31;

    for (int blk = 0; blk < 32; ++blk) {
        short8 kf[4];
        #pragma unroll
        for (int ks = 0; ks < 4; ++ks)
            kf[ks] = *(const short8*)&K[(size_t)(blk * 32 + qc) * 64 + ks * 16 + hi * 8];
        f32x16 s = {};
        #pragma unroll
        for (int ks = 0; ks < 4; ++ks)
            s = MFMA32(kf[ks], qf[ks], s);
        float e[16];
        #pragma unroll
        for (int r = 0; r < 16; ++r) e[r] = __expf(s[r]);

        const u16* Vb = V + (size_t)(half * 32 + qc) * NSEQ + blk * 32 + hi * 8;
        short8 v0 = *(const short8*)&Vb[0];
        short8 v1 = *(const short8*)&Vb[16];

        // selection: per-query mask (uniform across lane pair)
        const bool selb = (mask >> blk) & 1u;
        const unsigned selm = selb ? 0xFFFFFFFFu : 0u;
        {
            float t = 0.f;
            #pragma unroll
            for (int r = 0; r < 16; ++r) t += e[r];
            denS += selb ? t : 0.f;
        }
        short8 pb0, pb1;
        packswap(e, selm, pb0, pb1);
        aS = MFMA32(v0, pb0, aS);
        aS = MFMA32(v1, pb1, aS);

        if (blk >= wlo && blk <= whi) {
            float ew[16];
            float t = 0.f;
            #pragma unroll
            for (int r = 0; r < 16; ++r) {
                int kr = (r & 3) + 8 * (r >> 2) + 4 * hi;
                int dd = blk * 32 + kr - qrow;
                ew[r] = (dd >= -32 && dd <= 32) ? e[r] : 0.f;
                t += ew[r];
            }
            denW += t;
            short8 pw0, pw1;
            packswap(ew, 0xFFFFFFFFu, pw0, pw1);
            aW = MFMA32(v0, pw0, aW);
            aW = MFMA32(v1, pw1, aW);
        }
    }
    denS += __shfl_xor(denS, 32);
    denW += __shfl_xor(denW, 32);
    const float rc = g0 / denc, rs = g1 / denS, rw = g2 / denW;
    u16* op = att + (size_t)(b * 1024 + qrow) * NDIM + h * 64 + half * 32;
    #pragma unroll
    for (int c4 = 0; c4 < 4; ++c4) {
        int d0 = c4 * 8 + hi * 4;
        s16x4 w0;
        #pragma unroll
        for (int j = 0; j < 4; ++j)
            w0[j] = (short)f2b(rc * aC[c4 * 4 + j] + rs * aS[c4 * 4 + j] + rw * aW[c4 * 4 + j]);
        *(s16x4*)&op[d0] = w0;
    }
}

// ---------------- host ----------------
extern "C" void kernel_launch(void* const* d_in, const int* in_sizes, int n_in,
                              void* d_out, int out_size, void* d_ws, size_t ws_size,
                              hipStream_t stream)
{
    const float* x0    = (const float*)d_in[0];
    const float* ln1_g = (const float*)d_in[1];
    const float* ln1_b = (const float*)d_in[2];
    const float* Wq    = (const float*)d_in[3];
    const float* Wk    = (const float*)d_in[4];
    const float* Wv    = (const float*)d_in[5];
    const float* Wg    = (const float*)d_in[6];
    const float* bg    = (const float*)d_in[7];
    const float* Wo    = (const float*)d_in[8];
    const float* bo    = (const float*)d_in[9];
    const float* ln2_g = (const float*)d_in[10];
    const float* ln2_b = (const float*)d_in[11];
    const float* W1    = (const float*)d_in[12];
    const float* b1    = (const float*)d_in[13];
    const float* W2    = (const float*)d_in[14];
    const float* b2    = (const float*)d_in[15];
    float* xo = (float*)d_out;

    char* w = (char*)d_ws;
    auto alloc = [&](size_t bytes) { char* p = w; w += (bytes + 255) & ~(size_t)255; return p; };
    u16*   hbf   = (u16*)  alloc((size_t)NROWS * NDIM * 2);       // 4MB
    u16*   qb    = (u16*)  alloc((size_t)NBH * NSEQ * NDH * 2);   // 4MB
    u16*   kb    = (u16*)  alloc((size_t)NBH * NSEQ * NDH * 2);   // 4MB
    u16*   vt    = (u16*)  alloc((size_t)NBH * NDH * NSEQ * 2);   // 4MB
    u16*   att   = (u16*)  alloc((size_t)NROWS * NDIM * 2);       // 4MB
    float* gates = (float*)alloc((size_t)NROWS * NHEAD * 3 * 4);
    u16*   kc16  = (u16*)  alloc((size_t)NBH * NBLKC * NDH * 2);
    u16*   vct16 = (u16*)  alloc((size_t)NBH * NDH * NBLKC * 2);
    u16*   wqkvT = (u16*)  alloc((size_t)2 * 1536 * 512 * 2);
    u16*   woT   = (u16*)  alloc((size_t)2 * 512 * 512 * 2);
    u16*   w1T   = (u16*)  alloc((size_t)2 * 2048 * 512 * 2);
    u16*   w2T   = (u16*)  alloc((size_t)2 * 512 * 2048 * 2);
    u16*   mid   = (u16*)qb;  // alias: qb+kb+vt+att (16MB) dead during MLP; mid needs 16MB

    hipMemcpyAsync(xo, x0, (size_t)NROWS * NDIM * 4, hipMemcpyDeviceToDevice, stream);

    for (int l = 0; l < 2; ++l) {
        transpose_w<<<dim3(16, 16), 256, 0, stream>>>(Wq + (size_t)l * 512 * 512, wqkvT + (size_t)l * 1536 * 512,              512, 512);
        transpose_w<<<dim3(16, 16), 256, 0, stream>>>(Wk + (size_t)l * 512 * 512, wqkvT + (size_t)l * 1536 * 512 + 512 * 512,  512, 512);
        transpose_w<<<dim3(16, 16), 256, 0, stream>>>(Wv + (size_t)l * 512 * 512, wqkvT + (size_t)l * 1536 * 512 + 1024 * 512, 512, 512);
        transpose_w<<<dim3(16, 16), 256, 0, stream>>>(Wo + (size_t)l * 512 * 512, woT + (size_t)l * 512 * 512,                 512, 512);
        transpose_w<<<dim3(64, 16), 256, 0, stream>>>(W1 + (size_t)l * 512 * 2048, w1T + (size_t)l * 2048 * 512,               512, 2048);
        transpose_w<<<dim3(16, 64), 256, 0, stream>>>(W2 + (size_t)l * 2048 * 512, w2T + (size_t)l * 512 * 2048,               2048, 512);
    }

    for (int l = 0; l < 2; ++l) {
        ln_kernel<<<NROWS / 4, 256, 0, stream>>>(xo, ln1_g + l * NDIM, ln1_b + l * NDIM, hbf);
        gates_kernel<<<NROWS / 4, 256, 0, stream>>>(hbf, Wg + (size_t)l * NDIM * 24, bg + l * 24, gates);
        gemm_k<128, 128, EP_QKV><<<dim3(1536 / 128, NROWS / 128), 256, 0, stream>>>(
            hbf, wqkvT + (size_t)l * 1536 * 512, NROWS, 1536, 512,
            nullptr, nullptr, nullptr, qb, kb, vt);
        pool_kernel<<<(NBH * NBLKC * NDH) / 256, 256, 0, stream>>>(kb, vt, kc16, vct16);
        attn_mfma<<<1024, 128, 0, stream>>>(qb, kb, vt, kc16, vct16, gates, att);
        gemm_k<64, 64, EP_RES><<<dim3(512 / 64, NROWS / 64), 256, 0, stream>>>(
            att, woT + (size_t)l * 512 * 512, NROWS, 512, 512,
            bo + l * NDIM, xo, nullptr, nullptr, nullptr, nullptr);
        ln_kernel<<<NROWS / 4, 256, 0, stream>>>(xo, ln2_g + l * NDIM, ln2_b + l * NDIM, hbf);
        gemm_k<128, 128, EP_GELU><<<dim3(2048 / 128, NROWS / 128), 256, 0, stream>>>(
            hbf, w1T + (size_t)l * 2048 * 512, NROWS, 2048, 512,
            b1 + l * NMLP, nullptr, mid, nullptr, nullptr, nullptr);
        gemm_k<64, 64, EP_RES><<<dim3(512 / 64, NROWS / 64), 256, 0, stream>>>(
            mid, w2T + (size_t)l * 512 * 2048, NROWS, 512, 2048,
            b2 + l * NDIM, xo, nullptr, nullptr, nullptr, nullptr);
    }
}

// Round 6
// 385.245 us; speedup vs baseline: 10.2099x; 1.0432x over previous
//
#include <hip/hip_runtime.h>
#include <cstdint>
#include <cstddef>

typedef __attribute__((ext_vector_type(4))) float f32x4;
typedef __attribute__((ext_vector_type(16))) float f32x16;
typedef __attribute__((ext_vector_type(8))) short short8;
typedef __attribute__((ext_vector_type(4))) short s16x4;
typedef __attribute__((ext_vector_type(2))) int int2v;
typedef unsigned short u16;

#define DEVINL static __device__ __forceinline__
#define MFMA32(A,B,C) __builtin_amdgcn_mfma_f32_32x32x16_bf16(A,B,C,0,0,0)

constexpr int NBATCH = 4;
constexpr int NSEQ   = 1024;
constexpr int NDIM   = 512;
constexpr int NHEAD  = 8;
constexpr int NDH    = 64;
constexpr int NMLP   = 2048;
constexpr int NROWS  = NBATCH * NSEQ;   // 4096
constexpr int NBLKC  = 32;
constexpr int NBH    = NBATCH * NHEAD;  // 32

DEVINL float b2f(u16 u) { union { unsigned u; float f; } x; x.u = ((unsigned)u) << 16; return x.f; }
DEVINL u16 f2b(float v) {
    union { float f; unsigned u; } x; x.f = v;
    unsigned r = x.u + 0x7fff + ((x.u >> 16) & 1);
    return (u16)(r >> 16);
}

// async global -> LDS, 16 bytes per lane (dest must be linear in lane order)
DEVINL void gload16(const u16* g, u16* l)
{
    __builtin_amdgcn_global_load_lds(
        (const __attribute__((address_space(1))) void*)g,
        (__attribute__((address_space(3))) void*)l, 16, 0, 0);
}

// ---------------- LayerNorm -> bf16 ----------------
__global__ void __launch_bounds__(256) ln_kernel(const float* __restrict__ x,
    const float* __restrict__ gg, const float* __restrict__ bb, u16* __restrict__ out)
{
    int row = blockIdx.x * 4 + (threadIdx.x >> 6);
    int lane = threadIdx.x & 63;
    const float* xr = x + (size_t)row * NDIM + lane * 8;
    f32x4 a = *(const f32x4*)xr;
    f32x4 c = *(const f32x4*)(xr + 4);
    float xv[8] = { a[0], a[1], a[2], a[3], c[0], c[1], c[2], c[3] };
    float s = 0.f, s2 = 0.f;
    #pragma unroll
    for (int i = 0; i < 8; ++i) { s += xv[i]; s2 += xv[i] * xv[i]; }
    #pragma unroll
    for (int d = 1; d < 64; d <<= 1) { s += __shfl_xor(s, d); s2 += __shfl_xor(s2, d); }
    float mean = s * (1.f / NDIM);
    float var = s2 * (1.f / NDIM) - mean * mean;
    float rstd = rsqrtf(var + 1e-5f);
    const float* gp = gg + lane * 8;
    const float* bp = bb + lane * 8;
    short8 o;
    #pragma unroll
    for (int i = 0; i < 8; ++i)
        o[i] = (short)f2b((xv[i] - mean) * rstd * gp[i] + bp[i]);
    *(short8*)(out + (size_t)row * NDIM + lane * 8) = o;
}

// ---------------- weight transpose fp32[K][Nc] -> bf16[Nc][K] ----------------
__global__ void __launch_bounds__(256) transpose_w(const float* __restrict__ W,
    u16* __restrict__ WT, int K, int Nc)
{
    __shared__ float tile[32][33];
    int tx = threadIdx.x & 31;
    int ty = threadIdx.x >> 5;
    int n0 = blockIdx.x * 32, k0 = blockIdx.y * 32;
    #pragma unroll
    for (int r = 0; r < 4; ++r) {
        int kr = ty * 4 + r;
        tile[kr][tx] = W[(size_t)(k0 + kr) * Nc + n0 + tx];
    }
    __syncthreads();
    #pragma unroll
    for (int r = 0; r < 4; ++r) {
        int nr = ty * 4 + r;
        WT[(size_t)(n0 + nr) * K + k0 + tx] = f2b(tile[tx][nr]);
    }
}

// ---------------- gates = sigmoid(h @ Wg + bg): one wave per row ----------------
__global__ void __launch_bounds__(256) gates_kernel(const u16* __restrict__ h,
    const float* __restrict__ Wg, const float* __restrict__ bg, float* __restrict__ gates)
{
    int wid = threadIdx.x >> 6, lane = threadIdx.x & 63;
    int row = blockIdx.x * 4 + wid;
    short8 hv = *(const short8*)(h + (size_t)row * NDIM + lane * 8);
    float acc[24];
    #pragma unroll
    for (int c = 0; c < 24; ++c) acc[c] = 0.f;
    const float* wg = Wg + (size_t)(lane * 8) * 24;
    #pragma unroll
    for (int j = 0; j < 8; ++j) {
        float hj = b2f((u16)hv[j]);
        const float* wr = wg + j * 24;
        #pragma unroll
        for (int c = 0; c < 24; ++c) acc[c] += hj * wr[c];
    }
    #pragma unroll
    for (int d = 1; d < 64; d <<= 1) {
        #pragma unroll
        for (int c = 0; c < 24; ++c) acc[c] += __shfl_xor(acc[c], d);
    }
    float v = 0.f;
    #pragma unroll
    for (int c = 0; c < 24; ++c) if (lane == c) v = acc[c];
    if (lane < 24)
        gates[(size_t)row * 24 + lane] = 1.f / (1.f + __expf(-(v + bg[lane])));
}

// ---------------- block mean-pool of K/V -> bf16 kc16[m][d], vct16[d][m] ----------------
__global__ void __launch_bounds__(256) pool_kernel(const u16* __restrict__ kb,
    const u16* __restrict__ vt, u16* __restrict__ kc16, u16* __restrict__ vct16)
{
    int idx = blockIdx.x * 256 + threadIdx.x; // 65536
    int d = idx & 63, m = (idx >> 6) & 31, bh = idx >> 11;
    const u16* kp = kb + ((size_t)bh * NSEQ + m * 32) * NDH + d;
    float sk = 0.f;
    #pragma unroll 8
    for (int j = 0; j < 32; ++j) sk += b2f(kp[j * NDH]);
    const u16* vp = vt + (size_t)bh * 65536 + (size_t)d * NSEQ + m * 32;
    float sv = 0.f;
    #pragma unroll 8
    for (int j = 0; j < 32; ++j) sv += b2f(vp[j]);
    kc16[(size_t)bh * 2048 + m * 64 + d] = f2b(sk * (1.f / 32.f));
    vct16[(size_t)bh * 2048 + d * 32 + m] = f2b(sv * (1.f / 32.f));
}

// ---------------- bf16 MFMA GEMM: C = A[M,K] @ (BT[Nc,K])^T ----------------
enum { EP_QKV = 0, EP_GELU = 1, EP_RES = 2 };

template<int BM, int BN, int EPIL>
__global__ void __launch_bounds__(256) gemm_k(
    const u16* __restrict__ A, const u16* __restrict__ BT,
    int M, int Nc, int K,
    const float* __restrict__ bias,
    float* __restrict__ resout,
    u16* __restrict__ outb,
    u16* __restrict__ q16, u16* __restrict__ k16, u16* __restrict__ vt16)
{
    constexpr int BK = 32;
    constexpr int WM = BM / 2, WN = BN / 2;
    constexpr int MI = WM / 16, NI = WN / 16;
    __shared__ u16 As[BM][BK];
    __shared__ u16 Bs[BN][BK];
    const int tid = threadIdx.x;
    const int lane = tid & 63;
    const int wid = tid >> 6;
    const int wm = wid >> 1, wn = wid & 1;
    const int rowBase = blockIdx.y * BM;
    const int colBase = blockIdx.x * BN;
    const int fr = lane & 15;
    const int kg = lane >> 4;
    u16* aLin = &As[0][0];
    u16* bLin = &Bs[0][0];
    f32x4 acc[MI][NI] = {};

    for (int k0 = 0; k0 < K; k0 += BK) {
        __syncthreads();
        #pragma unroll
        for (int p = 0; p < BM / 64; ++p) {
            int idx = p * 256 + tid;
            gload16(&A[(size_t)(rowBase + (idx >> 2)) * K + k0 + (idx & 3) * 8], aLin + idx * 8);
        }
        #pragma unroll
        for (int p = 0; p < BN / 64; ++p) {
            int idx = p * 256 + tid;
            gload16(&BT[(size_t)(colBase + (idx >> 2)) * K + k0 + (idx & 3) * 8], bLin + idx * 8);
        }
        __syncthreads();
        short8 af[MI], bfr[NI];
        #pragma unroll
        for (int i = 0; i < MI; ++i)
            af[i] = *(const short8*)(&As[wm * WM + i * 16 + fr][kg * 8]);
        #pragma unroll
        for (int j = 0; j < NI; ++j)
            bfr[j] = *(const short8*)(&Bs[wn * WN + j * 16 + fr][kg * 8]);
        #pragma unroll
        for (int i = 0; i < MI; ++i)
            #pragma unroll
            for (int j = 0; j < NI; ++j)
                acc[i][j] = __builtin_amdgcn_mfma_f32_16x16x32_bf16(af[i], bfr[j], acc[i][j], 0, 0, 0);
    }

    #pragma unroll
    for (int i = 0; i < MI; ++i) {
        #pragma unroll
        for (int j = 0; j < NI; ++j) {
            int col = colBase + wn * WN + j * 16 + fr;
            if constexpr (EPIL == EP_QKV) {
                int which = col >> 9, c = col & 511;
                int hh = c >> 6, dh = c & 63;
                int row0 = rowBase + wm * WM + i * 16 + kg * 4;
                int bb2 = row0 >> 10, n0 = row0 & 1023;
                size_t bh2 = (size_t)(bb2 * NHEAD + hh) * 65536;
                if (which == 2) {
                    s16x4 pk;
                    #pragma unroll
                    for (int rr = 0; rr < 4; ++rr) pk[rr] = (short)f2b(acc[i][j][rr]);
                    *(s16x4*)&vt16[bh2 + (size_t)dh * NSEQ + n0] = pk;
                } else {
                    u16* dst = (which ? k16 : q16) + bh2 + (size_t)n0 * NDH + dh;
                    float scl = which ? 1.f : 0.125f;
                    #pragma unroll
                    for (int rr = 0; rr < 4; ++rr) dst[rr * NDH] = f2b(acc[i][j][rr] * scl);
                }
            } else {
                #pragma unroll
                for (int rr = 0; rr < 4; ++rr) {
                    int row = rowBase + wm * WM + i * 16 + kg * 4 + rr;
                    float val = acc[i][j][rr];
                    if constexpr (EPIL == EP_GELU) {
                        float t = val + bias[col];
                        float g = 0.5f * t * (1.f + tanhf(0.7978845608f * (t + 0.044715f * t * t * t)));
                        outb[(size_t)row * Nc + col] = f2b(g);
                    } else {
                        resout[(size_t)row * Nc + col] += val + bias[col];
                    }
                }
            }
        }
    }
}

// pack 2 f32 -> 1 word of 2 bf16 (RNE)
DEVINL unsigned cvtpk(float lo, float hi_)
{
    unsigned t;
    asm("v_cvt_pk_bf16_f32 %0, %1, %2" : "=v"(t) : "v"(lo), "v"(hi_));
    return t;
}

DEVINL void plswap(unsigned& a, unsigned& b)
{
#if __has_builtin(__builtin_amdgcn_permlane32_swap)
    int2v r = __builtin_amdgcn_permlane32_swap((int)a, (int)b, false, false);
    a = (unsigned)r[0]; b = (unsigned)r[1];
#else
    asm("v_permlane32_swap_b32 %0, %1" : "+v"(a), "+v"(b));
#endif
}

// e[16] (QK^T C-frag scores) -> PV B-frags pb0 (k=0..15), pb1 (k=16..31).
DEVINL void packswap(const float* e, unsigned selmask, short8& pb0, short8& pb1)
{
    unsigned w[8];
    #pragma unroll
    for (int i = 0; i < 8; ++i) w[i] = cvtpk(e[2 * i], e[2 * i + 1]) & selmask;
    plswap(w[0], w[2]); plswap(w[1], w[3]);
    plswap(w[4], w[6]); plswap(w[5], w[7]);
    union { unsigned u[4]; short8 s; } c0, c1;
    c0.u[0] = w[0]; c0.u[1] = w[1]; c0.u[2] = w[2]; c0.u[3] = w[3];
    c1.u[0] = w[4]; c1.u[1] = w[5]; c1.u[2] = w[6]; c1.u[3] = w[7];
    pb0 = c0.s; pb1 = c1.s;
}

// ---------------- MFMA attention: 4 waves per 32-query tile (d-half x kv-half) ----------------
__global__ void __launch_bounds__(256, 4) attn_mfma(
    const u16* __restrict__ qb, const u16* __restrict__ kb, const u16* __restrict__ vt,
    const u16* __restrict__ kc16, const u16* __restrict__ vct16,
    const float* __restrict__ gates, u16* __restrict__ att)
{
    __shared__ float cmb[2][64][35];
    const int tid = threadIdx.x;
    const int wid = tid >> 6;
    const int half = wid & 1;          // d-half
    const int kw = wid >> 1;           // kv-range half
    const int lane = tid & 63;
    const int qc = lane & 31, hi = lane >> 5;
    const int g = blockIdx.x;                  // 0..1023
    const int xcd = g & 7, ii = g >> 3;        // ii 0..127
    const int bh = xcd * 4 + (ii >> 5);
    const int qt = ii & 31;
    const int qrow = qt * 32 + qc;
    const u16* Q = qb + (size_t)bh * 65536;
    const u16* K = kb + (size_t)bh * 65536;
    const u16* V = vt + (size_t)bh * 65536;
    short8 qf[4];
    #pragma unroll
    for (int ks = 0; ks < 4; ++ks)
        qf[ks] = *(const short8*)&Q[(size_t)qrow * 64 + ks * 16 + hi * 8];
    const int b = bh >> 3, h = bh & 7;
    const float* grow = gates + (size_t)(b * 1024 + qrow) * 24 + h * 3;
    const float g0 = grow[0], g1 = grow[1], g2 = grow[2];

    // ================= compressed scores + top-8 bitmask (all waves) =================
    const u16* Kc = kc16 + (size_t)bh * 2048;   // [m][d]
    const u16* Vc = vct16 + (size_t)bh * 2048;  // [d][m]
    f32x16 sc_ = {};
    #pragma unroll
    for (int ks = 0; ks < 4; ++ks) {
        short8 kcf = *(const short8*)&Kc[qc * 64 + ks * 16 + hi * 8];
        sc_ = MFMA32(kcf, qf[ks], sc_);
    }
    float po[16];
    #pragma unroll
    for (int r = 0; r < 16; ++r) po[r] = __shfl_xor(sc_[r], 32);
    unsigned bits = 0;
    #pragma unroll
    for (int r = 0; r < 16; ++r) {
        const int krr = (r & 3) + 8 * (r >> 2);
        const float sr = sc_[r];
        int cnt = 0;
        #pragma unroll
        for (int j = 0; j < 16; ++j) {
            const int krj = (j & 3) + 8 * (j >> 2);
            if (j != r) cnt += (sc_[j] > sr || (sc_[j] == sr && krj < krr)) ? 1 : 0;
            const bool pless = (hi == 0) ? (krj + 4 < krr) : (krj < krr + 4);
            cnt += (po[j] > sr || (po[j] == sr && pless)) ? 1 : 0;
        }
        if (cnt < 8) bits |= 1u << (krr + 4 * hi);
    }
    const unsigned mask = bits | __shfl_xor(bits, 32);

    // compressed branch (kw==0 waves only)
    f32x16 aC = {};
    float denc = 1.f;
    if (kw == 0) {
        float ec[16]; float dsum = 0.f;
        #pragma unroll
        for (int r = 0; r < 16; ++r) { ec[r] = __expf(sc_[r]); dsum += ec[r]; }
        denc = dsum + __shfl_xor(dsum, 32);
        short8 pc0, pc1;
        packswap(ec, 0xFFFFFFFFu, pc0, pc1);
        const u16* Vch = Vc + (half * 32 + qc) * 32 + hi * 8;
        short8 vcA = *(const short8*)&Vch[0];
        short8 vcB = *(const short8*)&Vch[16];
        aC = MFMA32(vcA, pc0, aC);
        aC = MFMA32(vcB, pc1, aC);
    }

    // ================= selection + window branches (16 blocks per wave) =================
    f32x16 aS = {}, aW = {};
    float denS = 0.f, denW = 0.f;
    const int blo = kw * 16;
    const int wlo = qt > 0 ? qt - 1 : 0;
    const int whi = qt < 31 ? qt + 1 : 31;

    for (int t = 0; t < 16; ++t) {
        const int blk = blo + t;
        short8 kf[4];
        #pragma unroll
        for (int ks = 0; ks < 4; ++ks)
            kf[ks] = *(const short8*)&K[(size_t)(blk * 32 + qc) * 64 + ks * 16 + hi * 8];
        f32x16 s = {};
        #pragma unroll
        for (int ks = 0; ks < 4; ++ks)
            s = MFMA32(kf[ks], qf[ks], s);
        float e[16];
        #pragma unroll
        for (int r = 0; r < 16; ++r) e[r] = __expf(s[r]);

        const u16* Vb = V + (size_t)(half * 32 + qc) * NSEQ + blk * 32 + hi * 8;
        short8 v0 = *(const short8*)&Vb[0];
        short8 v1 = *(const short8*)&Vb[16];

        const bool selb = (mask >> blk) & 1u;
        const unsigned selm = selb ? 0xFFFFFFFFu : 0u;
        {
            float tt = 0.f;
            #pragma unroll
            for (int r = 0; r < 16; ++r) tt += e[r];
            denS += selb ? tt : 0.f;
        }
        short8 pb0, pb1;
        packswap(e, selm, pb0, pb1);
        aS = MFMA32(v0, pb0, aS);
        aS = MFMA32(v1, pb1, aS);

        if (blk >= wlo && blk <= whi) {
            float ew[16];
            float tt = 0.f;
            #pragma unroll
            for (int r = 0; r < 16; ++r) {
                int kr = (r & 3) + 8 * (r >> 2) + 4 * hi;
                int dd = blk * 32 + kr - qrow;
                ew[r] = (dd >= -32 && dd <= 32) ? e[r] : 0.f;
                tt += ew[r];
            }
            denW += tt;
            short8 pw0, pw1;
            packswap(ew, 0xFFFFFFFFu, pw0, pw1);
            aW = MFMA32(v0, pw0, aW);
            aW = MFMA32(v1, pw1, aW);
        }
    }

    // ================= cross-wave combine (kv halves) =================
    if (kw == 1) {
        float* dst = &cmb[half][lane][0];
        #pragma unroll
        for (int i = 0; i < 16; ++i) dst[i] = aS[i];
        #pragma unroll
        for (int i = 0; i < 16; ++i) dst[16 + i] = aW[i];
        dst[32] = denS; dst[33] = denW;
    }
    __syncthreads();
    if (kw == 0) {
        const float* src = &cmb[half][lane][0];
        #pragma unroll
        for (int i = 0; i < 16; ++i) aS[i] += src[i];
        #pragma unroll
        for (int i = 0; i < 16; ++i) aW[i] += src[16 + i];
        denS += src[32]; denW += src[33];
        denS += __shfl_xor(denS, 32);
        denW += __shfl_xor(denW, 32);
        const float rc = g0 / denc, rs = g1 / denS, rw = g2 / denW;
        u16* op = att + (size_t)(b * 1024 + qrow) * NDIM + h * 64 + half * 32;
        #pragma unroll
        for (int c4 = 0; c4 < 4; ++c4) {
            int d0 = c4 * 8 + hi * 4;
            s16x4 w0;
            #pragma unroll
            for (int j = 0; j < 4; ++j)
                w0[j] = (short)f2b(rc * aC[c4 * 4 + j] + rs * aS[c4 * 4 + j] + rw * aW[c4 * 4 + j]);
            *(s16x4*)&op[d0] = w0;
        }
    }
}

// ---------------- host ----------------
extern "C" void kernel_launch(void* const* d_in, const int* in_sizes, int n_in,
                              void* d_out, int out_size, void* d_ws, size_t ws_size,
                              hipStream_t stream)
{
    const float* x0    = (const float*)d_in[0];
    const float* ln1_g = (const float*)d_in[1];
    const float* ln1_b = (const float*)d_in[2];
    const float* Wq    = (const float*)d_in[3];
    const float* Wk    = (const float*)d_in[4];
    const float* Wv    = (const float*)d_in[5];
    const float* Wg    = (const float*)d_in[6];
    const float* bg    = (const float*)d_in[7];
    const float* Wo    = (const float*)d_in[8];
    const float* bo    = (const float*)d_in[9];
    const float* ln2_g = (const float*)d_in[10];
    const float* ln2_b = (const float*)d_in[11];
    const float* W1    = (const float*)d_in[12];
    const float* b1    = (const float*)d_in[13];
    const float* W2    = (const float*)d_in[14];
    const float* b2    = (const float*)d_in[15];
    float* xo = (float*)d_out;

    char* w = (char*)d_ws;
    auto alloc = [&](size_t bytes) { char* p = w; w += (bytes + 255) & ~(size_t)255; return p; };
    u16*   hbf   = (u16*)  alloc((size_t)NROWS * NDIM * 2);       // 4MB
    u16*   qb    = (u16*)  alloc((size_t)NBH * NSEQ * NDH * 2);   // 4MB
    u16*   kb    = (u16*)  alloc((size_t)NBH * NSEQ * NDH * 2);   // 4MB
    u16*   vt    = (u16*)  alloc((size_t)NBH * NDH * NSEQ * 2);   // 4MB
    u16*   att   = (u16*)  alloc((size_t)NROWS * NDIM * 2);       // 4MB
    float* gates = (float*)alloc((size_t)NROWS * NHEAD * 3 * 4);
    u16*   kc16  = (u16*)  alloc((size_t)NBH * NBLKC * NDH * 2);
    u16*   vct16 = (u16*)  alloc((size_t)NBH * NDH * NBLKC * 2);
    u16*   wqkvT = (u16*)  alloc((size_t)2 * 1536 * 512 * 2);
    u16*   woT   = (u16*)  alloc((size_t)2 * 512 * 512 * 2);
    u16*   w1T   = (u16*)  alloc((size_t)2 * 2048 * 512 * 2);
    u16*   w2T   = (u16*)  alloc((size_t)2 * 512 * 2048 * 2);
    u16*   mid   = (u16*)qb;  // alias: qb+kb+vt+att (16MB) dead during MLP; mid needs 16MB

    hipMemcpyAsync(xo, x0, (size_t)NROWS * NDIM * 4, hipMemcpyDeviceToDevice, stream);

    for (int l = 0; l < 2; ++l) {
        transpose_w<<<dim3(16, 16), 256, 0, stream>>>(Wq + (size_t)l * 512 * 512, wqkvT + (size_t)l * 1536 * 512,              512, 512);
        transpose_w<<<dim3(16, 16), 256, 0, stream>>>(Wk + (size_t)l * 512 * 512, wqkvT + (size_t)l * 1536 * 512 + 512 * 512,  512, 512);
        transpose_w<<<dim3(16, 16), 256, 0, stream>>>(Wv + (size_t)l * 512 * 512, wqkvT + (size_t)l * 1536 * 512 + 1024 * 512, 512, 512);
        transpose_w<<<dim3(16, 16), 256, 0, stream>>>(Wo + (size_t)l * 512 * 512, woT + (size_t)l * 512 * 512,                 512, 512);
        transpose_w<<<dim3(64, 16), 256, 0, stream>>>(W1 + (size_t)l * 512 * 2048, w1T + (size_t)l * 2048 * 512,               512, 2048);
        transpose_w<<<dim3(16, 64), 256, 0, stream>>>(W2 + (size_t)l * 2048 * 512, w2T + (size_t)l * 512 * 2048,               2048, 512);
    }

    for (int l = 0; l < 2; ++l) {
        ln_kernel<<<NROWS / 4, 256, 0, stream>>>(xo, ln1_g + l * NDIM, ln1_b + l * NDIM, hbf);
        gates_kernel<<<NROWS / 4, 256, 0, stream>>>(hbf, Wg + (size_t)l * NDIM * 24, bg + l * 24, gates);
        gemm_k<128, 128, EP_QKV><<<dim3(1536 / 128, NROWS / 128), 256, 0, stream>>>(
            hbf, wqkvT + (size_t)l * 1536 * 512, NROWS, 1536, 512,
            nullptr, nullptr, nullptr, qb, kb, vt);
        pool_kernel<<<(NBH * NBLKC * NDH) / 256, 256, 0, stream>>>(kb, vt, kc16, vct16);
        attn_mfma<<<1024, 256, 0, stream>>>(qb, kb, vt, kc16, vct16, gates, att);
        gemm_k<64, 64, EP_RES><<<dim3(512 / 64, NROWS / 64), 256, 0, stream>>>(
            att, woT + (size_t)l * 512 * 512, NROWS, 512, 512,
            bo + l * NDIM, xo, nullptr, nullptr, nullptr, nullptr);
        ln_kernel<<<NROWS / 4, 256, 0, stream>>>(xo, ln2_g + l * NDIM, ln2_b + l * NDIM, hbf);
        gemm_k<128, 128, EP_GELU><<<dim3(2048 / 128, NROWS / 128), 256, 0, stream>>>(
            hbf, w1T + (size_t)l * 2048 * 512, NROWS, 2048, 512,
            b1 + l * NMLP, nullptr, mid, nullptr, nullptr, nullptr);
        gemm_k<64, 64, EP_RES><<<dim3(512 / 64, NROWS / 64), 256, 0, stream>>>(
            mid, w2T + (size_t)l * 512 * 2048, NROWS, 512, 2048,
            b2 + l * NDIM, xo, nullptr, nullptr, nullptr, nullptr);
    }
}

// Round 7
// 362.438 us; speedup vs baseline: 10.8523x; 1.0629x over previous
//
#include <hip/hip_runtime.h>
#include <cstdint>
#include <cstddef>

typedef __attribute__((ext_vector_type(4))) float f32x4;
typedef __attribute__((ext_vector_type(16))) float f32x16;
typedef __attribute__((ext_vector_type(8))) short short8;
typedef __attribute__((ext_vector_type(4))) short s16x4;
typedef __attribute__((ext_vector_type(2))) int int2v;
typedef unsigned short u16;

#define DEVINL static __device__ __forceinline__
#define MFMA32(A,B,C) __builtin_amdgcn_mfma_f32_32x32x16_bf16(A,B,C,0,0,0)

constexpr int NBATCH = 4;
constexpr int NSEQ   = 1024;
constexpr int NDIM   = 512;
constexpr int NHEAD  = 8;
constexpr int NDH    = 64;
constexpr int NMLP   = 2048;
constexpr int NROWS  = NBATCH * NSEQ;   // 4096
constexpr int NBLKC  = 32;
constexpr int NBH    = NBATCH * NHEAD;  // 32

DEVINL float b2f(u16 u) { union { unsigned u; float f; } x; x.u = ((unsigned)u) << 16; return x.f; }
DEVINL u16 f2b(float v) {
    union { float f; unsigned u; } x; x.f = v;
    unsigned r = x.u + 0x7fff + ((x.u >> 16) & 1);
    return (u16)(r >> 16);
}

// async global -> LDS, 16 bytes per lane (dest linear in lane order)
DEVINL void gload16(const u16* g, u16* l)
{
    __builtin_amdgcn_global_load_lds(
        (const __attribute__((address_space(1))) void*)g,
        (__attribute__((address_space(3))) void*)l, 16, 0, 0);
}

// ---------------- LayerNorm -> bf16 (ln2) ----------------
__global__ void __launch_bounds__(256) ln_kernel(const float* __restrict__ x,
    const float* __restrict__ gg, const float* __restrict__ bb, u16* __restrict__ out)
{
    int row = blockIdx.x * 4 + (threadIdx.x >> 6);
    int lane = threadIdx.x & 63;
    const float* xr = x + (size_t)row * NDIM + lane * 8;
    f32x4 a = *(const f32x4*)xr;
    f32x4 c = *(const f32x4*)(xr + 4);
    float xv[8] = { a[0], a[1], a[2], a[3], c[0], c[1], c[2], c[3] };
    float s = 0.f, s2 = 0.f;
    #pragma unroll
    for (int i = 0; i < 8; ++i) { s += xv[i]; s2 += xv[i] * xv[i]; }
    #pragma unroll
    for (int d = 1; d < 64; d <<= 1) { s += __shfl_xor(s, d); s2 += __shfl_xor(s2, d); }
    float mean = s * (1.f / NDIM);
    float var = s2 * (1.f / NDIM) - mean * mean;
    float rstd = rsqrtf(var + 1e-5f);
    const float* gp = gg + lane * 8;
    const float* bp = bb + lane * 8;
    short8 o;
    #pragma unroll
    for (int i = 0; i < 8; ++i)
        o[i] = (short)f2b((xv[i] - mean) * rstd * gp[i] + bp[i]);
    *(short8*)(out + (size_t)row * NDIM + lane * 8) = o;
}

// ---------------- fused LN1 + gates ----------------
__global__ void __launch_bounds__(256) ln_gates_kernel(const float* __restrict__ x,
    const float* __restrict__ gg, const float* __restrict__ bb,
    const float* __restrict__ Wg, const float* __restrict__ bg,
    u16* __restrict__ out, float* __restrict__ gates)
{
    int row = blockIdx.x * 4 + (threadIdx.x >> 6);
    int lane = threadIdx.x & 63;
    const float* xr = x + (size_t)row * NDIM + lane * 8;
    f32x4 a = *(const f32x4*)xr;
    f32x4 c = *(const f32x4*)(xr + 4);
    float xv[8] = { a[0], a[1], a[2], a[3], c[0], c[1], c[2], c[3] };
    float s = 0.f, s2 = 0.f;
    #pragma unroll
    for (int i = 0; i < 8; ++i) { s += xv[i]; s2 += xv[i] * xv[i]; }
    #pragma unroll
    for (int d = 1; d < 64; d <<= 1) { s += __shfl_xor(s, d); s2 += __shfl_xor(s2, d); }
    float mean = s * (1.f / NDIM);
    float var = s2 * (1.f / NDIM) - mean * mean;
    float rstd = rsqrtf(var + 1e-5f);
    const float* gp = gg + lane * 8;
    const float* bp = bb + lane * 8;
    float hv[8];
    short8 o;
    #pragma unroll
    for (int i = 0; i < 8; ++i) {
        hv[i] = (xv[i] - mean) * rstd * gp[i] + bp[i];
        o[i] = (short)f2b(hv[i]);
    }
    *(short8*)(out + (size_t)row * NDIM + lane * 8) = o;
    // gates
    float acc[24];
    #pragma unroll
    for (int c2 = 0; c2 < 24; ++c2) acc[c2] = 0.f;
    const float* wg = Wg + (size_t)(lane * 8) * 24;
    #pragma unroll
    for (int j = 0; j < 8; ++j) {
        const float* wr = wg + j * 24;
        #pragma unroll
        for (int c2 = 0; c2 < 24; ++c2) acc[c2] += hv[j] * wr[c2];
    }
    #pragma unroll
    for (int d = 1; d < 64; d <<= 1) {
        #pragma unroll
        for (int c2 = 0; c2 < 24; ++c2) acc[c2] += __shfl_xor(acc[c2], d);
    }
    float v = 0.f;
    #pragma unroll
    for (int c2 = 0; c2 < 24; ++c2) if (lane == c2) v = acc[c2];
    if (lane < 24)
        gates[(size_t)row * 24 + lane] = 1.f / (1.f + __expf(-(v + bg[lane])));
}

// ---------------- weight transposes fp32[K][Nc] -> bf16[Nc][K], batched over z ----------------
__global__ void __launch_bounds__(256) transpose_w(const float* __restrict__ W,
    u16* __restrict__ WT, int K, int Nc, size_t sstr, size_t dstr)
{
    W  += (size_t)blockIdx.z * sstr;
    WT += (size_t)blockIdx.z * dstr;
    __shared__ float tile[32][33];
    int tx = threadIdx.x & 31;
    int ty = threadIdx.x >> 5;
    int n0 = blockIdx.x * 32, k0 = blockIdx.y * 32;
    #pragma unroll
    for (int r = 0; r < 4; ++r) {
        int kr = ty * 4 + r;
        tile[kr][tx] = W[(size_t)(k0 + kr) * Nc + n0 + tx];
    }
    __syncthreads();
    #pragma unroll
    for (int r = 0; r < 4; ++r) {
        int nr = ty * 4 + r;
        WT[(size_t)(n0 + nr) * K + k0 + tx] = f2b(tile[tx][nr]);
    }
}

__global__ void __launch_bounds__(256) transpose_qkv(const float* __restrict__ Wq,
    const float* __restrict__ Wk, const float* __restrict__ Wv, u16* __restrict__ WT)
{
    int z = blockIdx.z;                 // 0..5 = l*3 + which
    int l = z / 3, w = z % 3;
    const float* W = (w == 0 ? Wq : (w == 1 ? Wk : Wv)) + (size_t)l * 262144;
    u16* dst = WT + (size_t)z * 262144;
    __shared__ float tile[32][33];
    int tx = threadIdx.x & 31;
    int ty = threadIdx.x >> 5;
    int n0 = blockIdx.x * 32, k0 = blockIdx.y * 32;
    #pragma unroll
    for (int r = 0; r < 4; ++r) {
        int kr = ty * 4 + r;
        tile[kr][tx] = W[(size_t)(k0 + kr) * 512 + n0 + tx];
    }
    __syncthreads();
    #pragma unroll
    for (int r = 0; r < 4; ++r) {
        int nr = ty * 4 + r;
        dst[(size_t)(n0 + nr) * 512 + k0 + tx] = f2b(tile[tx][nr]);
    }
}

// ---------------- block mean-pool of K/V -> bf16 kc16[m][d], vct16[d][m] ----------------
__global__ void __launch_bounds__(256) pool_kernel(const u16* __restrict__ kb,
    const u16* __restrict__ vt, u16* __restrict__ kc16, u16* __restrict__ vct16)
{
    int idx = blockIdx.x * 256 + threadIdx.x; // 65536
    int d = idx & 63, m = (idx >> 6) & 31, bh = idx >> 11;
    const u16* kp = kb + ((size_t)bh * NSEQ + m * 32) * NDH + d;
    float sk = 0.f;
    #pragma unroll 8
    for (int j = 0; j < 32; ++j) sk += b2f(kp[j * NDH]);
    const u16* vp = vt + (size_t)bh * 65536 + (size_t)d * NSEQ + m * 32;
    float sv = 0.f;
    #pragma unroll 8
    for (int j = 0; j < 32; ++j) sv += b2f(vp[j]);
    kc16[(size_t)bh * 2048 + m * 64 + d] = f2b(sk * (1.f / 32.f));
    vct16[(size_t)bh * 2048 + d * 32 + m] = f2b(sv * (1.f / 32.f));
}

// ---------------- bf16 MFMA GEMM: C = A[M,K] @ (BT[Nc,K])^T ----------------
enum { EP_QKV = 0, EP_GELU = 1, EP_RES = 2 };

template<int BM, int BN, int NK, int EPIL>
__global__ void __launch_bounds__(256) gemm_k(
    const u16* __restrict__ A, const u16* __restrict__ BT,
    int M, int Nc, int K,
    const float* __restrict__ bias,
    float* __restrict__ resout,
    u16* __restrict__ outb,
    u16* __restrict__ q16, u16* __restrict__ k16, u16* __restrict__ vt16)
{
    constexpr int BK = 32 * NK;
    constexpr int WM = BM / 2, WN = BN / 2;
    constexpr int MI = WM / 16, NI = WN / 16;
    __shared__ u16 As[BM][BK];
    __shared__ u16 Bs[BN][BK];
    const int tid = threadIdx.x;
    const int lane = tid & 63;
    const int wid = tid >> 6;
    const int wm = wid >> 1, wn = wid & 1;
    const int rowBase = blockIdx.y * BM;
    const int colBase = blockIdx.x * BN;
    const int fr = lane & 15;
    const int kg = lane >> 4;
    u16* aLin = &As[0][0];
    u16* bLin = &Bs[0][0];
    f32x4 acc[MI][NI] = {};

    for (int k0 = 0; k0 < K; k0 += BK) {
        __syncthreads();
        #pragma unroll
        for (int p = 0; p < BM * NK / 64; ++p) {
            int idx = p * 256 + tid;
            gload16(&A[(size_t)(rowBase + idx / (BK / 8)) * K + k0 + (idx % (BK / 8)) * 8], aLin + idx * 8);
        }
        #pragma unroll
        for (int p = 0; p < BN * NK / 64; ++p) {
            int idx = p * 256 + tid;
            gload16(&BT[(size_t)(colBase + idx / (BK / 8)) * K + k0 + (idx % (BK / 8)) * 8], bLin + idx * 8);
        }
        __syncthreads();
        #pragma unroll
        for (int kk = 0; kk < NK; ++kk) {
            short8 af[MI], bfr[NI];
            #pragma unroll
            for (int i = 0; i < MI; ++i)
                af[i] = *(const short8*)(&As[wm * WM + i * 16 + fr][kk * 32 + kg * 8]);
            #pragma unroll
            for (int j = 0; j < NI; ++j)
                bfr[j] = *(const short8*)(&Bs[wn * WN + j * 16 + fr][kk * 32 + kg * 8]);
            #pragma unroll
            for (int i = 0; i < MI; ++i)
                #pragma unroll
                for (int j = 0; j < NI; ++j)
                    acc[i][j] = __builtin_amdgcn_mfma_f32_16x16x32_bf16(af[i], bfr[j], acc[i][j], 0, 0, 0);
        }
    }

    #pragma unroll
    for (int i = 0; i < MI; ++i) {
        #pragma unroll
        for (int j = 0; j < NI; ++j) {
            int col = colBase + wn * WN + j * 16 + fr;
            if constexpr (EPIL == EP_QKV) {
                int which = col >> 9, c = col & 511;
                int hh = c >> 6, dh = c & 63;
                int row0 = rowBase + wm * WM + i * 16 + kg * 4;
                int bb2 = row0 >> 10, n0 = row0 & 1023;
                size_t bh2 = (size_t)(bb2 * NHEAD + hh) * 65536;
                if (which == 2) {
                    s16x4 pk;
                    #pragma unroll
                    for (int rr = 0; rr < 4; ++rr) pk[rr] = (short)f2b(acc[i][j][rr]);
                    *(s16x4*)&vt16[bh2 + (size_t)dh * NSEQ + n0] = pk;
                } else {
                    u16* dst = (which ? k16 : q16) + bh2 + (size_t)n0 * NDH + dh;
                    // q pre-scaled by DH^-0.5 * log2(e) so attn uses exp2 directly
                    float scl = which ? 1.f : 0.18033688f;
                    #pragma unroll
                    for (int rr = 0; rr < 4; ++rr) dst[rr * NDH] = f2b(acc[i][j][rr] * scl);
                }
            } else {
                #pragma unroll
                for (int rr = 0; rr < 4; ++rr) {
                    int row = rowBase + wm * WM + i * 16 + kg * 4 + rr;
                    float val = acc[i][j][rr];
                    if constexpr (EPIL == EP_GELU) {
                        float t = val + bias[col];
                        float g = 0.5f * t * (1.f + tanhf(0.7978845608f * (t + 0.044715f * t * t * t)));
                        outb[(size_t)row * Nc + col] = f2b(g);
                    } else {
                        resout[(size_t)row * Nc + col] += val + bias[col];
                    }
                }
            }
        }
    }
}

// pack 2 f32 -> 1 word of 2 bf16 (RNE)
DEVINL unsigned cvtpk(float lo, float hi_)
{
    unsigned t;
    asm("v_cvt_pk_bf16_f32 %0, %1, %2" : "=v"(t) : "v"(lo), "v"(hi_));
    return t;
}

DEVINL void plswap(unsigned& a, unsigned& b)
{
#if __has_builtin(__builtin_amdgcn_permlane32_swap)
    int2v r = __builtin_amdgcn_permlane32_swap((int)a, (int)b, false, false);
    a = (unsigned)r[0]; b = (unsigned)r[1];
#else
    asm("v_permlane32_swap_b32 %0, %1" : "+v"(a), "+v"(b));
#endif
}

// e[16] (QK^T C-frag scores) -> PV B-frags pb0 (k=0..15), pb1 (k=16..31).
DEVINL void packswap(const float* e, unsigned selmask, short8& pb0, short8& pb1)
{
    unsigned w[8];
    #pragma unroll
    for (int i = 0; i < 8; ++i) w[i] = cvtpk(e[2 * i], e[2 * i + 1]) & selmask;
    plswap(w[0], w[2]); plswap(w[1], w[3]);
    plswap(w[4], w[6]); plswap(w[5], w[7]);
    union { unsigned u[4]; short8 s; } c0, c1;
    c0.u[0] = w[0]; c0.u[1] = w[1]; c0.u[2] = w[2]; c0.u[3] = w[3];
    c1.u[0] = w[4]; c1.u[1] = w[5]; c1.u[2] = w[6]; c1.u[3] = w[7];
    pb0 = c0.s; pb1 = c1.s;
}

// rank 4 rows (R0..R0+3) of this wave's scores; returns partial selection bits
template<int R0>
DEVINL unsigned rank4(const f32x16& sc_, const float* po, int hi)
{
    unsigned bits = 0;
    #pragma unroll
    for (int k = 0; k < 4; ++k) {
        const int r = R0 + k;
        const int krr = (r & 3) + 8 * (r >> 2);
        const float sr = sc_[r];
        int cnt = 0;
        #pragma unroll
        for (int j = 0; j < 16; ++j) {
            const int krj = (j & 3) + 8 * (j >> 2);
            if (j != r) cnt += (sc_[j] > sr || (sc_[j] == sr && krj < krr)) ? 1 : 0;
            const bool pless = (hi == 0) ? (krj + 4 < krr) : (krj < krr + 4);
            cnt += (po[j] > sr || (po[j] == sr && pless)) ? 1 : 0;
        }
        if (cnt < 8) bits |= 1u << (krr + 4 * hi);
    }
    return bits;
}

// ---------------- MFMA attention: 4 waves per 32-query tile (d-half x kv-half) ----------------
__global__ void __launch_bounds__(256, 4) attn_mfma(
    const u16* __restrict__ qb, const u16* __restrict__ kb, const u16* __restrict__ vt,
    const u16* __restrict__ kc16, const u16* __restrict__ vct16,
    const float* __restrict__ gates, u16* __restrict__ att)
{
    __shared__ float cmb[2][64][35];
    __shared__ unsigned selb_lds[32];
    const int tid = threadIdx.x;
    const int wid = tid >> 6;
    const int half = wid & 1;          // d-half
    const int kw = wid >> 1;           // kv-range half
    const int lane = tid & 63;
    const int qc = lane & 31, hi = lane >> 5;
    const int g = blockIdx.x;                  // 0..1023
    const int xcd = g & 7, ii = g >> 3;        // ii 0..127
    const int bh = xcd * 4 + (ii >> 5);
    const int qt = ii & 31;
    const int qrow = qt * 32 + qc;
    if (tid < 32) selb_lds[tid] = 0u;
    const u16* Q = qb + (size_t)bh * 65536;
    const u16* K = kb + (size_t)bh * 65536;
    const u16* V = vt + (size_t)bh * 65536;
    short8 qf[4];
    #pragma unroll
    for (int ks = 0; ks < 4; ++ks)
        qf[ks] = *(const short8*)&Q[(size_t)qrow * 64 + ks * 16 + hi * 8];
    const int b = bh >> 3, h = bh & 7;
    const float* grow = gates + (size_t)(b * 1024 + qrow) * 24 + h * 3;
    const float g0 = grow[0], g1 = grow[1], g2 = grow[2];

    // ================= compressed scores (all waves; scores pre-scaled for exp2) ==========
    const u16* Kc = kc16 + (size_t)bh * 2048;   // [m][d]
    const u16* Vc = vct16 + (size_t)bh * 2048;  // [d][m]
    f32x16 sc_ = {};
    #pragma unroll
    for (int ks = 0; ks < 4; ++ks) {
        short8 kcf = *(const short8*)&Kc[qc * 64 + ks * 16 + hi * 8];
        sc_ = MFMA32(kcf, qf[ks], sc_);
    }
    float po[16];
    #pragma unroll
    for (int r = 0; r < 16; ++r) po[r] = __shfl_xor(sc_[r], 32);
    // partial ranking: this wave ranks rows R0..R0+3
    unsigned bits;
    switch (wid) {
        case 0:  bits = rank4<0>(sc_, po, hi); break;
        case 1:  bits = rank4<4>(sc_, po, hi); break;
        case 2:  bits = rank4<8>(sc_, po, hi); break;
        default: bits = rank4<12>(sc_, po, hi); break;
    }
    __syncthreads();                      // selb_lds zero-init complete
    atomicOr(&selb_lds[qc], bits);

    // compressed branch (kw==0 waves; overlaps with mask combine)
    f32x16 aC = {};
    float denc = 1.f;
    if (kw == 0) {
        float ec[16]; float dsum = 0.f;
        #pragma unroll
        for (int r = 0; r < 16; ++r) { ec[r] = exp2f(sc_[r]); dsum += ec[r]; }
        denc = dsum + __shfl_xor(dsum, 32);
        short8 pc0, pc1;
        packswap(ec, 0xFFFFFFFFu, pc0, pc1);
        const u16* Vch = Vc + (half * 32 + qc) * 32 + hi * 8;
        short8 vcA = *(const short8*)&Vch[0];
        short8 vcB = *(const short8*)&Vch[16];
        aC = MFMA32(vcA, pc0, aC);
        aC = MFMA32(vcB, pc1, aC);
    }
    __syncthreads();                      // all partial ORs complete
    const unsigned mask = selb_lds[qc];

    // ================= selection + window branches (16 blocks per wave) =================
    f32x16 aS = {}, aW = {};
    float denS = 0.f, denW = 0.f;
    const int blo = kw * 16;
    const int wlo = qt > 0 ? qt - 1 : 0;
    const int whi = qt < 31 ? qt + 1 : 31;

    for (int t = 0; t < 16; ++t) {
        const int blk = blo + t;
        short8 kf[4];
        #pragma unroll
        for (int ks = 0; ks < 4; ++ks)
            kf[ks] = *(const short8*)&K[(size_t)(blk * 32 + qc) * 64 + ks * 16 + hi * 8];
        f32x16 s = {};
        #pragma unroll
        for (int ks = 0; ks < 4; ++ks)
            s = MFMA32(kf[ks], qf[ks], s);
        float e[16];
        #pragma unroll
        for (int r = 0; r < 16; ++r) e[r] = exp2f(s[r]);

        const u16* Vb = V + (size_t)(half * 32 + qc) * NSEQ + blk * 32 + hi * 8;
        short8 v0 = *(const short8*)&Vb[0];
        short8 v1 = *(const short8*)&Vb[16];

        const bool selb = (mask >> blk) & 1u;
        const unsigned selm = selb ? 0xFFFFFFFFu : 0u;
        {
            float tt = 0.f;
            #pragma unroll
            for (int r = 0; r < 16; ++r) tt += e[r];
            denS += selb ? tt : 0.f;
        }
        short8 pb0, pb1;
        packswap(e, selm, pb0, pb1);
        aS = MFMA32(v0, pb0, aS);
        aS = MFMA32(v1, pb1, aS);

        if (blk >= wlo && blk <= whi) {
            float ew[16];
            float tt = 0.f;
            #pragma unroll
            for (int r = 0; r < 16; ++r) {
                int kr = (r & 3) + 8 * (r >> 2) + 4 * hi;
                int dd = blk * 32 + kr - qrow;
                ew[r] = (dd >= -32 && dd <= 32) ? e[r] : 0.f;
                tt += ew[r];
            }
            denW += tt;
            short8 pw0, pw1;
            packswap(ew, 0xFFFFFFFFu, pw0, pw1);
            aW = MFMA32(v0, pw0, aW);
            aW = MFMA32(v1, pw1, aW);
        }
    }

    // ================= cross-wave combine (kv halves) =================
    if (kw == 1) {
        float* dst = &cmb[half][lane][0];
        #pragma unroll
        for (int i = 0; i < 16; ++i) dst[i] = aS[i];
        #pragma unroll
        for (int i = 0; i < 16; ++i) dst[16 + i] = aW[i];
        dst[32] = denS; dst[33] = denW;
    }
    __syncthreads();
    if (kw == 0) {
        const float* src = &cmb[half][lane][0];
        #pragma unroll
        for (int i = 0; i < 16; ++i) aS[i] += src[i];
        #pragma unroll
        for (int i = 0; i < 16; ++i) aW[i] += src[16 + i];
        denS += src[32]; denW += src[33];
        denS += __shfl_xor(denS, 32);
        denW += __shfl_xor(denW, 32);
        const float rc = g0 / denc, rs = g1 / denS, rw = g2 / denW;
        u16* op = att + (size_t)(b * 1024 + qrow) * NDIM + h * 64 + half * 32;
        #pragma unroll
        for (int c4 = 0; c4 < 4; ++c4) {
            int d0 = c4 * 8 + hi * 4;
            s16x4 w0;
            #pragma unroll
            for (int j = 0; j < 4; ++j)
                w0[j] = (short)f2b(rc * aC[c4 * 4 + j] + rs * aS[c4 * 4 + j] + rw * aW[c4 * 4 + j]);
            *(s16x4*)&op[d0] = w0;
        }
    }
}

// ---------------- host ----------------
extern "C" void kernel_launch(void* const* d_in, const int* in_sizes, int n_in,
                              void* d_out, int out_size, void* d_ws, size_t ws_size,
                              hipStream_t stream)
{
    const float* x0    = (const float*)d_in[0];
    const float* ln1_g = (const float*)d_in[1];
    const float* ln1_b = (const float*)d_in[2];
    const float* Wq    = (const float*)d_in[3];
    const float* Wk    = (const float*)d_in[4];
    const float* Wv    = (const float*)d_in[5];
    const float* Wg    = (const float*)d_in[6];
    const float* bg    = (const float*)d_in[7];
    const float* Wo    = (const float*)d_in[8];
    const float* bo    = (const float*)d_in[9];
    const float* ln2_g = (const float*)d_in[10];
    const float* ln2_b = (const float*)d_in[11];
    const float* W1    = (const float*)d_in[12];
    const float* b1    = (const float*)d_in[13];
    const float* W2    = (const float*)d_in[14];
    const float* b2    = (const float*)d_in[15];
    float* xo = (float*)d_out;

    char* w = (char*)d_ws;
    auto alloc = [&](size_t bytes) { char* p = w; w += (bytes + 255) & ~(size_t)255; return p; };
    u16*   hbf   = (u16*)  alloc((size_t)NROWS * NDIM * 2);       // 4MB
    u16*   qb    = (u16*)  alloc((size_t)NBH * NSEQ * NDH * 2);   // 4MB
    u16*   kb    = (u16*)  alloc((size_t)NBH * NSEQ * NDH * 2);   // 4MB
    u16*   vt    = (u16*)  alloc((size_t)NBH * NDH * NSEQ * 2);   // 4MB
    u16*   att   = (u16*)  alloc((size_t)NROWS * NDIM * 2);       // 4MB
    float* gates = (float*)alloc((size_t)NROWS * NHEAD * 3 * 4);
    u16*   kc16  = (u16*)  alloc((size_t)NBH * NBLKC * NDH * 2);
    u16*   vct16 = (u16*)  alloc((size_t)NBH * NDH * NBLKC * 2);
    u16*   wqkvT = (u16*)  alloc((size_t)2 * 1536 * 512 * 2);
    u16*   woT   = (u16*)  alloc((size_t)2 * 512 * 512 * 2);
    u16*   w1T   = (u16*)  alloc((size_t)2 * 2048 * 512 * 2);
    u16*   w2T   = (u16*)  alloc((size_t)2 * 512 * 2048 * 2);
    u16*   mid   = (u16*)qb;  // alias: qb+kb+vt+att (16MB) dead during MLP; mid needs 16MB

    hipMemcpyAsync(xo, x0, (size_t)NROWS * NDIM * 4, hipMemcpyDeviceToDevice, stream);

    transpose_qkv<<<dim3(16, 16, 6), 256, 0, stream>>>(Wq, Wk, Wv, wqkvT);
    transpose_w<<<dim3(16, 16, 2), 256, 0, stream>>>(Wo, woT, 512, 512,  262144, 262144);
    transpose_w<<<dim3(64, 16, 2), 256, 0, stream>>>(W1, w1T, 512, 2048, 1048576, 1048576);
    transpose_w<<<dim3(16, 64, 2), 256, 0, stream>>>(W2, w2T, 2048, 512, 1048576, 1048576);

    for (int l = 0; l < 2; ++l) {
        ln_gates_kernel<<<NROWS / 4, 256, 0, stream>>>(xo, ln1_g + l * NDIM, ln1_b + l * NDIM,
            Wg + (size_t)l * NDIM * 24, bg + l * 24, hbf, gates);
        gemm_k<128, 128, 1, EP_QKV><<<dim3(1536 / 128, NROWS / 128), 256, 0, stream>>>(
            hbf, wqkvT + (size_t)l * 1536 * 512, NROWS, 1536, 512,
            nullptr, nullptr, nullptr, qb, kb, vt);
        pool_kernel<<<(NBH * NBLKC * NDH) / 256, 256, 0, stream>>>(kb, vt, kc16, vct16);
        attn_mfma<<<1024, 256, 0, stream>>>(qb, kb, vt, kc16, vct16, gates, att);
        gemm_k<64, 64, 2, EP_RES><<<dim3(512 / 64, NROWS / 64), 256, 0, stream>>>(
            att, woT + (size_t)l * 512 * 512, NROWS, 512, 512,
            bo + l * NDIM, xo, nullptr, nullptr, nullptr, nullptr);
        ln_kernel<<<NROWS / 4, 256, 0, stream>>>(xo, ln2_g + l * NDIM, ln2_b + l * NDIM, hbf);
        gemm_k<128, 128, 1, EP_GELU><<<dim3(2048 / 128, NROWS / 128), 256, 0, stream>>>(
            hbf, w1T + (size_t)l * 2048 * 512, NROWS, 2048, 512,
            b1 + l * NMLP, nullptr, mid, nullptr, nullptr, nullptr);
        gemm_k<64, 64, 2, EP_RES><<<dim3(512 / 64, NROWS / 64), 256, 0, stream>>>(
            mid, w2T + (size_t)l * 512 * 2048, NROWS, 512, 2048,
            b2 + l * NDIM, xo, nullptr, nullptr, nullptr, nullptr);
    }
}